// Round 3
// baseline (1407.689 us; speedup 1.0000x reference)
//
#include <hip/hip_runtime.h>
#include <hip/hip_bf16.h>
#include <math.h>

// Problem constants
#define B_    2
#define S_    2048
#define D_    1024
#define NH_   16
#define NKV_  4
#define HD_   64
#define NTOK  (B_ * S_)                       // 4096
#define QKVN  (NH_ * HD_ + 2 * NKV_ * HD_)    // 1536
#define REP   (NH_ / NKV_)                    // 4

typedef __attribute__((ext_vector_type(8))) short short8;   // 8 bf16 (4 VGPRs), MFMA A/B frag
typedef __attribute__((ext_vector_type(4))) float f32x4;    // MFMA C/D frag

// Static device scratch, all fully rewritten each call.
__device__ short          g_xb[(size_t)NTOK * D_];               //  8.4 MB bf16 x
__device__ short          g_wqkv[(size_t)QKVN * D_];             //  3.1 MB bf16 [Wq;Wk;Wv]
__device__ short          g_wob[(size_t)D_ * NH_ * HD_];         //  2.1 MB bf16 Wo
__device__ float          g_yqkv[(size_t)NTOK * QKVN];           // 25.2 MB fp32 QKV proj
__device__ float          g_q[(size_t)B_ * NH_  * S_ * HD_];     // 16.8 MB roped Q [b][h][s][d]
__device__ float          g_k[(size_t)B_ * NKV_ * S_ * HD_];     //  4.2 MB roped K
__device__ float          g_v[(size_t)B_ * NKV_ * S_ * HD_];     //  4.2 MB V
__device__ __hip_bfloat16 g_ao[(size_t)NTOK * NH_ * HD_];        //  8.4 MB attn out [tok][h*64+d]

static __device__ inline short f2bf(float f) {
  __hip_bfloat16 h = __float2bfloat16(f);     // RNE
  return *reinterpret_cast<short*>(&h);
}

// ---------------------------------------------------------------------------
// fp32 -> bf16 conversion of x and all weights (float4 in, short4 out).
// Region map (in float4 units): x | Wq | Wk | Wv | Wo.
// ---------------------------------------------------------------------------
#define NX4   (NTOK * D_ / 4)                 // 1048576
#define NWQ4  (NH_ * HD_ * D_ / 4)            //  262144
#define NWK4  (NKV_ * HD_ * D_ / 4)           //   65536
#define NWV4  NWK4
#define NWO4  (D_ * NH_ * HD_ / 4)            //  262144
#define NCVT  (NX4 + NWQ4 + NWK4 + NWV4 + NWO4)

__global__ __launch_bounds__(256) void convert_all(const float* __restrict__ x,
                                                   const float* __restrict__ wq,
                                                   const float* __restrict__ wk,
                                                   const float* __restrict__ wv,
                                                   const float* __restrict__ wo) {
  int i = blockIdx.x * blockDim.x + threadIdx.x;
  if (i >= NCVT) return;
  const float* src; short* dst; int off;
  if (i < NX4)                          { src = x;  dst = g_xb;   off = i; }
  else if (i < NX4 + NWQ4)              { src = wq; dst = g_wqkv; off = i - NX4; }
  else if (i < NX4 + NWQ4 + NWK4)       { src = wk; dst = g_wqkv + (size_t)NWQ4 * 4;          off = i - NX4 - NWQ4; }
  else if (i < NX4 + NWQ4 + NWK4 + NWV4){ src = wv; dst = g_wqkv + (size_t)(NWQ4 + NWK4) * 4; off = i - NX4 - NWQ4 - NWK4; }
  else                                  { src = wo; dst = g_wob;  off = i - NX4 - NWQ4 - NWK4 - NWV4; }
  float4 v = ((const float4*)src)[off];
  short4 s;
  s.x = f2bf(v.x); s.y = f2bf(v.y); s.z = f2bf(v.z); s.w = f2bf(v.w);
  ((short4*)dst)[off] = s;
}

// ---------------------------------------------------------------------------
// GEMM1: g_yqkv[4096][1536] = xb[4096][1024] @ wqkv[1536][1024]^T  (bf16 MFMA)
// Block: 256 thr = 4 waves; wave = 32(M) x 64(N); block = 128(M) x 64(N).
// ---------------------------------------------------------------------------
__global__ __launch_bounds__(256) void gemm_qkv() {
  const int w = threadIdx.x >> 6, lane = threadIdx.x & 63;
  const int m0 = blockIdx.x * 128 + w * 32;
  const int n0 = blockIdx.y * 64;
  const int lr = lane & 15, lk = (lane >> 4) * 8;

  f32x4 acc[2][4] = {};
  for (int k0 = 0; k0 < D_; k0 += 32) {
    short8 a0 = *(const short8*)(g_xb + (size_t)(m0 + lr) * D_ + k0 + lk);
    short8 a1 = *(const short8*)(g_xb + (size_t)(m0 + 16 + lr) * D_ + k0 + lk);
#pragma unroll
    for (int bj = 0; bj < 4; ++bj) {
      short8 bf = *(const short8*)(g_wqkv + (size_t)(n0 + bj * 16 + lr) * D_ + k0 + lk);
      acc[0][bj] = __builtin_amdgcn_mfma_f32_16x16x32_bf16(a0, bf, acc[0][bj], 0, 0, 0);
      acc[1][bj] = __builtin_amdgcn_mfma_f32_16x16x32_bf16(a1, bf, acc[1][bj], 0, 0, 0);
    }
  }
  const int rb = (lane >> 4) * 4;
#pragma unroll
  for (int af = 0; af < 2; ++af)
#pragma unroll
    for (int bj = 0; bj < 4; ++bj)
#pragma unroll
      for (int r = 0; r < 4; ++r)
        g_yqkv[(size_t)(m0 + af * 16 + rb + r) * QKVN + n0 + bj * 16 + lr] =
            acc[af][bj][r];
}

// ---------------------------------------------------------------------------
// RoPE + scatter q,k into [b][head][s][d] fp32. One thread per (tok, head, d<32).
// ---------------------------------------------------------------------------
__global__ void rope_scatter() {
  int idx = blockIdx.x * blockDim.x + threadIdx.x;
  if (idx >= NTOK * (NH_ + NKV_) * 32) return;
  const int d    = idx & 31;
  const int head = (idx >> 5) % (NH_ + NKV_);
  const int tok  = idx / ((NH_ + NKV_) * 32);
  const int b = tok / S_, s = tok % S_;

  const float* src;
  float* dst;
  if (head < NH_) {
    src = g_yqkv + (size_t)tok * QKVN + head * HD_;
    dst = g_q + (((size_t)(b * NH_ + head)) * S_ + s) * HD_;
  } else {
    const int kvh = head - NH_;
    src = g_yqkv + (size_t)tok * QKVN + NH_ * HD_ + kvh * HD_;
    dst = g_k + (((size_t)(b * NKV_ + kvh)) * S_ + s) * HD_;
  }
  const float x1 = src[d], x2 = src[d + 32];
  // inv_freq = 10000^(-d/32) = 2^(-d * log2(10000)/32)
  const float inv = exp2f((float)d * (-13.287712379549449f / 32.0f));
  const float ang = (float)s * inv;
  float sn, cs;
  sincosf(ang, &sn, &cs);   // accurate range reduction (ang up to ~2047 rad)
  dst[d]      = x1 * cs - x2 * sn;
  dst[d + 32] = x2 * cs + x1 * sn;
}

// V scatter into [b][kvh][s][d] fp32
__global__ void v_scatter() {
  int idx = blockIdx.x * blockDim.x + threadIdx.x;
  if (idx >= NTOK * NKV_ * HD_) return;
  const int d   = idx & 63;
  const int kvh = (idx >> 6) & 3;
  const int tok = idx >> 8;
  const int b = tok / S_, s = tok % S_;
  g_v[(((size_t)(b * NKV_ + kvh)) * S_ + s) * HD_ + d] =
      g_yqkv[(size_t)tok * QKVN + NH_ * HD_ + NKV_ * HD_ + kvh * HD_ + d];
}

// ---------------------------------------------------------------------------
// Causal flash attention (vector VALU, fp32). 1 wave / block; thread = one q row.
// Grid: (B*NH, S/64). K/V tiles 64x64 fp32 staged in LDS (32 KiB).
// ---------------------------------------------------------------------------
__global__ __launch_bounds__(64) void attn() {
  const int bh  = blockIdx.x;            // 0..31
  const int b   = bh / NH_, h = bh % NH_;
  const int kvh = h / REP;
  const int q0  = blockIdx.y * 64;
  const int tid = threadIdx.x;
  const int qi  = q0 + tid;

  __shared__ float Kt[64][64];
  __shared__ float Vt[64][64];

  const float scale = 0.125f;            // 1/sqrt(64)
  float qreg[64];
  const float* qptr = g_q + (((size_t)bh) * S_ + qi) * HD_;
#pragma unroll
  for (int d = 0; d < 64; d += 4) {
    float4 t = *(const float4*)(qptr + d);
    qreg[d] = t.x * scale; qreg[d + 1] = t.y * scale;
    qreg[d + 2] = t.z * scale; qreg[d + 3] = t.w * scale;
  }

  float m_run = -1e30f, l = 0.0f;
  float o[64];
#pragma unroll
  for (int d = 0; d < 64; ++d) o[d] = 0.0f;

  const float* Kbase = g_k + ((size_t)(b * NKV_ + kvh)) * S_ * HD_;
  const float* Vbase = g_v + ((size_t)(b * NKV_ + kvh)) * S_ * HD_;

  const int nt = blockIdx.y + 1;         // causal: tiles 0..blockIdx.y
  for (int t = 0; t < nt; ++t) {
    __syncthreads();
    const float* krow = Kbase + (size_t)(t * 64 + tid) * HD_;
    const float* vrow = Vbase + (size_t)(t * 64 + tid) * HD_;
#pragma unroll
    for (int d = 0; d < 64; d += 4) {
      *(float4*)&Kt[tid][d] = *(const float4*)(krow + d);
      *(float4*)&Vt[tid][d] = *(const float4*)(vrow + d);
    }
    __syncthreads();

    const int kmax = qi - t * 64;        // kk <= kmax valid (>=0 always)
    for (int kk = 0; kk < 64; ++kk) {
      float a0 = 0.f, a1 = 0.f, a2 = 0.f, a3 = 0.f;
#pragma unroll
      for (int d = 0; d < 64; d += 4) {
        float4 k4 = *(const float4*)&Kt[kk][d];
        a0 = fmaf(qreg[d],     k4.x, a0);
        a1 = fmaf(qreg[d + 1], k4.y, a1);
        a2 = fmaf(qreg[d + 2], k4.z, a2);
        a3 = fmaf(qreg[d + 3], k4.w, a3);
      }
      float sv = (a0 + a1) + (a2 + a3);
      if (kk > kmax) sv = -1e30f;        // masked: exp underflows to 0
      if (sv > m_run) {                  // rare rescale (online softmax)
        const float alpha = __expf(m_run - sv);
        l *= alpha;
#pragma unroll
        for (int d = 0; d < 64; ++d) o[d] *= alpha;
        m_run = sv;
      }
      const float p = __expf(sv - m_run);
      l += p;
#pragma unroll
      for (int d = 0; d < 64; d += 4) {
        float4 v4 = *(const float4*)&Vt[kk][d];
        o[d]     = fmaf(p, v4.x, o[d]);
        o[d + 1] = fmaf(p, v4.y, o[d + 1]);
        o[d + 2] = fmaf(p, v4.z, o[d + 2]);
        o[d + 3] = fmaf(p, v4.w, o[d + 3]);
      }
    }
  }

  const float inv_l = 1.0f / l;
  __hip_bfloat16* optr = g_ao + ((size_t)(b * S_ + qi)) * (NH_ * HD_) + h * HD_;
#pragma unroll
  for (int d = 0; d < 64; ++d) optr[d] = __float2bfloat16(o[d] * inv_l);
}

// ---------------------------------------------------------------------------
// GEMM2: out[4096][1024] = g_ao[4096][1024] @ wob[1024][1024]^T, fp32 out
// ---------------------------------------------------------------------------
__global__ __launch_bounds__(256) void gemm_out(float* __restrict__ out) {
  const int w = threadIdx.x >> 6, lane = threadIdx.x & 63;
  const int m0 = blockIdx.x * 128 + w * 32;
  const int n0 = blockIdx.y * 64;
  const int lr = lane & 15, lk = (lane >> 4) * 8;
  const short* A = (const short*)g_ao;
  const int K = NH_ * HD_;               // 1024

  f32x4 acc[2][4] = {};
  for (int k0 = 0; k0 < K; k0 += 32) {
    short8 a0 = *(const short8*)(A + (size_t)(m0 + lr) * K + k0 + lk);
    short8 a1 = *(const short8*)(A + (size_t)(m0 + 16 + lr) * K + k0 + lk);
#pragma unroll
    for (int bj = 0; bj < 4; ++bj) {
      short8 bf = *(const short8*)(g_wob + (size_t)(n0 + bj * 16 + lr) * K + k0 + lk);
      acc[0][bj] = __builtin_amdgcn_mfma_f32_16x16x32_bf16(a0, bf, acc[0][bj], 0, 0, 0);
      acc[1][bj] = __builtin_amdgcn_mfma_f32_16x16x32_bf16(a1, bf, acc[1][bj], 0, 0, 0);
    }
  }
  const int rb = (lane >> 4) * 4;
#pragma unroll
  for (int af = 0; af < 2; ++af)
#pragma unroll
    for (int bj = 0; bj < 4; ++bj)
#pragma unroll
      for (int r = 0; r < 4; ++r)
        out[(size_t)(m0 + af * 16 + rb + r) * D_ + n0 + bj * 16 + lr] =
            acc[af][bj][r];
}

// ---------------------------------------------------------------------------
extern "C" void kernel_launch(void* const* d_in, const int* in_sizes, int n_in,
                              void* d_out, int out_size, void* d_ws, size_t ws_size,
                              hipStream_t stream) {
  const float* x  = (const float*)d_in[0];   // float32 per reference
  const float* Wq = (const float*)d_in[1];
  const float* Wk = (const float*)d_in[2];
  const float* Wv = (const float*)d_in[3];
  const float* Wo = (const float*)d_in[4];
  float* out = (float*)d_out;

  {
    convert_all<<<(NCVT + 255) / 256, 256, 0, stream>>>(x, Wq, Wk, Wv, Wo);
  }
  {
    dim3 g(NTOK / 128, QKVN / 64);            // 32 x 24
    gemm_qkv<<<g, 256, 0, stream>>>();
  }
  {
    int n = NTOK * (NH_ + NKV_) * 32;         // 2.62M
    rope_scatter<<<(n + 255) / 256, 256, 0, stream>>>();
  }
  {
    int n = NTOK * NKV_ * HD_;                // 1.05M
    v_scatter<<<(n + 255) / 256, 256, 0, stream>>>();
  }
  {
    dim3 g(B_ * NH_, S_ / 64);                // 32 x 32, 64 threads
    attn<<<g, 64, 0, stream>>>();
  }
  {
    dim3 g(NTOK / 128, D_ / 64);              // 32 x 16
    gemm_out<<<g, 256, 0, stream>>>(out);
  }
}

// Round 4
// 358.527 us; speedup vs baseline: 3.9263x; 3.9263x over previous
//
#include <hip/hip_runtime.h>
#include <hip/hip_bf16.h>
#include <math.h>

// Problem constants
#define B_    2
#define S_    2048
#define D_    1024
#define NH_   16
#define NKV_  4
#define HD_   64
#define NTOK  (B_ * S_)                       // 4096
#define QKVN  (NH_ * HD_ + 2 * NKV_ * HD_)    // 1536
#define REP   (NH_ / NKV_)                    // 4

typedef __attribute__((ext_vector_type(8))) short short8;   // 8 bf16 (4 VGPRs), MFMA A/B frag
typedef __attribute__((ext_vector_type(4))) float f32x4;    // MFMA C/D frag

// Static device scratch, all fully rewritten each call.
__device__ short  g_xb[(size_t)NTOK * D_];               //  8.4 MB bf16 x
__device__ short  g_wqkv[(size_t)QKVN * D_];             //  3.1 MB bf16 [Wq;Wk;Wv]
__device__ short  g_wob[(size_t)D_ * NH_ * HD_];         //  2.1 MB bf16 Wo
__device__ float  g_yqkv[(size_t)NTOK * QKVN];           // 25.2 MB fp32 QKV proj
__device__ short  g_qb[(size_t)B_ * NH_  * S_ * HD_];    //  8.4 MB bf16 roped Q [b][h][s][d], pre-scaled 1/8
__device__ short  g_kb[(size_t)B_ * NKV_ * S_ * HD_];    //  2.1 MB bf16 roped K [b][kvh][s][d]
__device__ short  g_vt[(size_t)B_ * NKV_ * HD_ * S_];    //  2.1 MB bf16 V^T    [b][kvh][d][s]
__device__ short  g_ao[(size_t)NTOK * NH_ * HD_];        //  8.4 MB bf16 attn out [tok][h*64+d]

static __device__ inline short f2bf(float f) {
  __hip_bfloat16 h = __float2bfloat16(f);     // RNE
  return *reinterpret_cast<short*>(&h);
}

// ---------------------------------------------------------------------------
// fp32 -> bf16 conversion of x and all weights (float4 in, short4 out).
// ---------------------------------------------------------------------------
#define NX4   (NTOK * D_ / 4)                 // 1048576
#define NWQ4  (NH_ * HD_ * D_ / 4)            //  262144
#define NWK4  (NKV_ * HD_ * D_ / 4)           //   65536
#define NWV4  NWK4
#define NWO4  (D_ * NH_ * HD_ / 4)            //  262144
#define NCVT  (NX4 + NWQ4 + NWK4 + NWV4 + NWO4)

__global__ __launch_bounds__(256) void convert_all(const float* __restrict__ x,
                                                   const float* __restrict__ wq,
                                                   const float* __restrict__ wk,
                                                   const float* __restrict__ wv,
                                                   const float* __restrict__ wo) {
  int i = blockIdx.x * blockDim.x + threadIdx.x;
  if (i >= NCVT) return;
  const float* src; short* dst; int off;
  if (i < NX4)                          { src = x;  dst = g_xb;   off = i; }
  else if (i < NX4 + NWQ4)              { src = wq; dst = g_wqkv; off = i - NX4; }
  else if (i < NX4 + NWQ4 + NWK4)       { src = wk; dst = g_wqkv + (size_t)NWQ4 * 4;          off = i - NX4 - NWQ4; }
  else if (i < NX4 + NWQ4 + NWK4 + NWV4){ src = wv; dst = g_wqkv + (size_t)(NWQ4 + NWK4) * 4; off = i - NX4 - NWQ4 - NWK4; }
  else                                  { src = wo; dst = g_wob;  off = i - NX4 - NWQ4 - NWK4 - NWV4; }
  float4 v = ((const float4*)src)[off];
  short4 s;
  s.x = f2bf(v.x); s.y = f2bf(v.y); s.z = f2bf(v.z); s.w = f2bf(v.w);
  ((short4*)dst)[off] = s;
}

// ---------------------------------------------------------------------------
// GEMM1: g_yqkv[4096][1536] = xb[4096][1024] @ wqkv[1536][1024]^T  (bf16 MFMA)
// ---------------------------------------------------------------------------
__global__ __launch_bounds__(256) void gemm_qkv() {
  const int w = threadIdx.x >> 6, lane = threadIdx.x & 63;
  const int m0 = blockIdx.x * 128 + w * 32;
  const int n0 = blockIdx.y * 64;
  const int lr = lane & 15, lk = (lane >> 4) * 8;

  f32x4 acc[2][4] = {};
  for (int k0 = 0; k0 < D_; k0 += 32) {
    short8 a0 = *(const short8*)(g_xb + (size_t)(m0 + lr) * D_ + k0 + lk);
    short8 a1 = *(const short8*)(g_xb + (size_t)(m0 + 16 + lr) * D_ + k0 + lk);
#pragma unroll
    for (int bj = 0; bj < 4; ++bj) {
      short8 bf = *(const short8*)(g_wqkv + (size_t)(n0 + bj * 16 + lr) * D_ + k0 + lk);
      acc[0][bj] = __builtin_amdgcn_mfma_f32_16x16x32_bf16(a0, bf, acc[0][bj], 0, 0, 0);
      acc[1][bj] = __builtin_amdgcn_mfma_f32_16x16x32_bf16(a1, bf, acc[1][bj], 0, 0, 0);
    }
  }
  const int rb = (lane >> 4) * 4;
#pragma unroll
  for (int af = 0; af < 2; ++af)
#pragma unroll
    for (int bj = 0; bj < 4; ++bj)
#pragma unroll
      for (int r = 0; r < 4; ++r)
        g_yqkv[(size_t)(m0 + af * 16 + rb + r) * QKVN + n0 + bj * 16 + lr] =
            acc[af][bj][r];
}

// ---------------------------------------------------------------------------
// RoPE + scatter q,k -> bf16 [b][head][s][d]. One thread per (tok, head, d<32).
// Q additionally pre-scaled by 1/sqrt(HD) = 0.125 (exact in bf16).
// ---------------------------------------------------------------------------
__global__ void rope_scatter() {
  int idx = blockIdx.x * blockDim.x + threadIdx.x;
  if (idx >= NTOK * (NH_ + NKV_) * 32) return;
  const int d    = idx & 31;
  const int head = (idx >> 5) % (NH_ + NKV_);
  const int tok  = idx / ((NH_ + NKV_) * 32);
  const int b = tok / S_, s = tok % S_;

  const float* src;
  short* dst;
  float qscale;
  if (head < NH_) {
    src = g_yqkv + (size_t)tok * QKVN + head * HD_;
    dst = g_qb + (((size_t)(b * NH_ + head)) * S_ + s) * HD_;
    qscale = 0.125f;
  } else {
    const int kvh = head - NH_;
    src = g_yqkv + (size_t)tok * QKVN + NH_ * HD_ + kvh * HD_;
    dst = g_kb + (((size_t)(b * NKV_ + kvh)) * S_ + s) * HD_;
    qscale = 1.0f;
  }
  const float x1 = src[d], x2 = src[d + 32];
  const float inv = exp2f((float)d * (-13.287712379549449f / 32.0f));
  const float ang = (float)s * inv;
  float sn, cs;
  sincosf(ang, &sn, &cs);
  dst[d]      = f2bf((x1 * cs - x2 * sn) * qscale);
  dst[d + 32] = f2bf((x2 * cs + x1 * sn) * qscale);
}

// V scatter -> transposed bf16 [b][kvh][d][s]
__global__ void vt_scatter() {
  int idx = blockIdx.x * blockDim.x + threadIdx.x;
  if (idx >= B_ * NKV_ * HD_ * S_) return;
  const int s   = idx & (S_ - 1);
  const int d   = (idx >> 11) & 63;
  const int kvh = (idx >> 17) & 3;
  const int b   = idx >> 19;
  const float v = g_yqkv[(size_t)(b * S_ + s) * QKVN + NH_ * HD_ + NKV_ * HD_ + kvh * HD_ + d];
  g_vt[(((size_t)(b * NKV_ + kvh)) * HD_ + d) * S_ + s] = f2bf(v);
}

// ---------------------------------------------------------------------------
// MFMA flash attention, causal, GQA. Each wave: 16 q rows, independent (no LDS).
// Swapped QK^T: St = mfma(K, Q) -> St[kv][q], lane holds q = lane&15.
// PV: O^T = mfma(V^T, P^T) with P^T built via 16 shfls.
// Block = 4 waves = one 64-row q tile of one (b,h). Grid (bh, qt reversed).
// ---------------------------------------------------------------------------
__global__ __launch_bounds__(256) void attn_mfma() {
  const int bh  = blockIdx.x;                  // 0..31
  const int b   = bh >> 4, h = bh & 15;
  const int kvh = h >> 2;                      // REP = 4
  const int qt  = (int)(gridDim.y - 1 - blockIdx.y);   // heavy tiles dispatch first
  const int w   = threadIdx.x >> 6;
  const int lane = threadIdx.x & 63;
  const int g = lane >> 4, l = lane & 15;
  const int q0 = qt * 64 + w * 16;
  const int q_glob = q0 + l;

  const short* Qb = g_qb + ((size_t)bh * S_ + q0) * HD_;
  const short* Kb = g_kb + ((size_t)(b * NKV_ + kvh)) * S_ * HD_;
  const short* Vt = g_vt + ((size_t)(b * NKV_ + kvh)) * HD_ * S_;

  short8 qf[2];
  qf[0] = *(const short8*)(Qb + l * HD_ + g * 8);
  qf[1] = *(const short8*)(Qb + l * HD_ + 32 + g * 8);

  f32x4 o[4] = {};                             // O^T acc: d = df*16 + g*4 + r, q = l
  float m_run = -1e30f, l_run = 0.0f;

  const int nt = (q0 >> 5) + 1;                // kv tiles of 32
  for (int t = 0; t < nt; ++t) {
    // ---- QK^T (swapped): St[kv][q]
    f32x4 st[2] = {};
    const short* Kt = Kb + (size_t)(t * 32) * HD_;
#pragma unroll
    for (int ks = 0; ks < 2; ++ks) {
      short8 k0 = *(const short8*)(Kt + l * HD_ + ks * 32 + g * 8);
      short8 k1 = *(const short8*)(Kt + (16 + l) * HD_ + ks * 32 + g * 8);
      st[0] = __builtin_amdgcn_mfma_f32_16x16x32_bf16(k0, qf[ks], st[0], 0, 0, 0);
      st[1] = __builtin_amdgcn_mfma_f32_16x16x32_bf16(k1, qf[ks], st[1], 0, 0, 0);
    }
    // ---- mask + online softmax (per lane: 8 scores of column q = l)
    float sv[2][4];
    float mt = -1e30f;
#pragma unroll
    for (int mf = 0; mf < 2; ++mf)
#pragma unroll
      for (int r = 0; r < 4; ++r) {
        const int kv = t * 32 + mf * 16 + g * 4 + r;
        float s = st[mf][r];
        s = (kv > q_glob) ? -1e30f : s;
        sv[mf][r] = s;
        mt = fmaxf(mt, s);
      }
    mt = fmaxf(mt, __shfl_xor(mt, 16, 64));
    mt = fmaxf(mt, __shfl_xor(mt, 32, 64));
    const float m_new = fmaxf(m_run, mt);
    const float alpha = __expf(m_run - m_new);
    float p[2][4];
    float ls = 0.0f;
#pragma unroll
    for (int mf = 0; mf < 2; ++mf)
#pragma unroll
      for (int r = 0; r < 4; ++r) {
        const float pv = __expf(sv[mf][r] - m_new);
        p[mf][r] = pv;
        ls += pv;
      }
    ls += __shfl_xor(ls, 16, 64);
    ls += __shfl_xor(ls, 32, 64);
    l_run = l_run * alpha + ls;
    m_run = m_new;
#pragma unroll
    for (int df = 0; df < 4; ++df)
#pragma unroll
      for (int r = 0; r < 4; ++r) o[df][r] *= alpha;

    // ---- build P^T B-frag: pt[j] = P[q=l][kv_local = 8g + j]
    // source lane = l + 32*(g&1) + 16*(j>>2), register p[g>>1][j&3]
    short8 pt;
#pragma unroll
    for (int j = 0; j < 8; ++j) {
      const int src = l + ((lane >> 4 & 1) << 5) + ((j >> 2) << 4);
      const float v0 = __shfl(p[0][j & 3], src, 64);
      const float v1 = __shfl(p[1][j & 3], src, 64);
      pt[j] = f2bf((g & 2) ? v1 : v0);
    }
    // ---- PV: O^T += V^T @ P^T
#pragma unroll
    for (int df = 0; df < 4; ++df) {
      short8 vf = *(const short8*)(Vt + (size_t)(df * 16 + l) * S_ + t * 32 + g * 8);
      o[df] = __builtin_amdgcn_mfma_f32_16x16x32_bf16(vf, pt, o[df], 0, 0, 0);
    }
  }

  const float inv_l = 1.0f / l_run;
  short* optr = g_ao + ((size_t)(b * S_ + q_glob)) * (NH_ * HD_) + h * HD_;
#pragma unroll
  for (int df = 0; df < 4; ++df) {
    short4 s4;
    s4.x = f2bf(o[df][0] * inv_l);
    s4.y = f2bf(o[df][1] * inv_l);
    s4.z = f2bf(o[df][2] * inv_l);
    s4.w = f2bf(o[df][3] * inv_l);
    *(short4*)(optr + df * 16 + g * 4) = s4;
  }
}

// ---------------------------------------------------------------------------
// GEMM2: out[4096][1024] = g_ao[4096][1024] @ wob[1024][1024]^T, fp32 out
// ---------------------------------------------------------------------------
__global__ __launch_bounds__(256) void gemm_out(float* __restrict__ out) {
  const int w = threadIdx.x >> 6, lane = threadIdx.x & 63;
  const int m0 = blockIdx.x * 128 + w * 32;
  const int n0 = blockIdx.y * 64;
  const int lr = lane & 15, lk = (lane >> 4) * 8;
  const int K = NH_ * HD_;               // 1024

  f32x4 acc[2][4] = {};
  for (int k0 = 0; k0 < K; k0 += 32) {
    short8 a0 = *(const short8*)(g_ao + (size_t)(m0 + lr) * K + k0 + lk);
    short8 a1 = *(const short8*)(g_ao + (size_t)(m0 + 16 + lr) * K + k0 + lk);
#pragma unroll
    for (int bj = 0; bj < 4; ++bj) {
      short8 bf = *(const short8*)(g_wob + (size_t)(n0 + bj * 16 + lr) * K + k0 + lk);
      acc[0][bj] = __builtin_amdgcn_mfma_f32_16x16x32_bf16(a0, bf, acc[0][bj], 0, 0, 0);
      acc[1][bj] = __builtin_amdgcn_mfma_f32_16x16x32_bf16(a1, bf, acc[1][bj], 0, 0, 0);
    }
  }
  const int rb = (lane >> 4) * 4;
#pragma unroll
  for (int af = 0; af < 2; ++af)
#pragma unroll
    for (int bj = 0; bj < 4; ++bj)
#pragma unroll
      for (int r = 0; r < 4; ++r)
        out[(size_t)(m0 + af * 16 + rb + r) * D_ + n0 + bj * 16 + lr] =
            acc[af][bj][r];
}

// ---------------------------------------------------------------------------
extern "C" void kernel_launch(void* const* d_in, const int* in_sizes, int n_in,
                              void* d_out, int out_size, void* d_ws, size_t ws_size,
                              hipStream_t stream) {
  const float* x  = (const float*)d_in[0];   // float32 per reference
  const float* Wq = (const float*)d_in[1];
  const float* Wk = (const float*)d_in[2];
  const float* Wv = (const float*)d_in[3];
  const float* Wo = (const float*)d_in[4];
  float* out = (float*)d_out;

  convert_all<<<(NCVT + 255) / 256, 256, 0, stream>>>(x, Wq, Wk, Wv, Wo);
  {
    dim3 g(NTOK / 128, QKVN / 64);            // 32 x 24
    gemm_qkv<<<g, 256, 0, stream>>>();
  }
  {
    int n = NTOK * (NH_ + NKV_) * 32;         // 2.62M
    rope_scatter<<<(n + 255) / 256, 256, 0, stream>>>();
  }
  {
    int n = B_ * NKV_ * HD_ * S_;             // 1.05M
    vt_scatter<<<(n + 255) / 256, 256, 0, stream>>>();
  }
  {
    dim3 g(B_ * NH_, S_ / 64);                // 32 bh x 32 qtiles, 4 waves each
    attn_mfma<<<g, 256, 0, stream>>>();
  }
  {
    dim3 g(NTOK / 128, D_ / 64);              // 32 x 16
    gemm_out<<<g, 256, 0, stream>>>(out);
  }
}

// Round 5
// 327.110 us; speedup vs baseline: 4.3034x; 1.0960x over previous
//
#include <hip/hip_runtime.h>
#include <hip/hip_bf16.h>
#include <math.h>

// Problem constants
#define B_    2
#define S_    2048
#define D_    1024
#define NH_   16
#define NKV_  4
#define HD_   64
#define NTOK  (B_ * S_)                       // 4096
#define QKVN  (NH_ * HD_ + 2 * NKV_ * HD_)    // 1536
#define REP   (NH_ / NKV_)                    // 4

#define LOG2E 1.4426950408889634f

typedef __attribute__((ext_vector_type(8))) short short8;   // 8 bf16 (4 VGPRs), MFMA A/B frag
typedef __attribute__((ext_vector_type(4))) float f32x4;    // MFMA C/D frag

// Static device scratch, all fully rewritten each call.
__device__ short  g_xb[(size_t)NTOK * D_];               //  8.4 MB bf16 x
__device__ short  g_wqkv[(size_t)QKVN * D_];             //  3.1 MB bf16 [Wq;Wk;Wv]
__device__ short  g_wob[(size_t)D_ * NH_ * HD_];         //  2.1 MB bf16 Wo
__device__ float  g_rc[(size_t)S_ * 32];                 //  256 KB cos table [s][d<32]
__device__ float  g_rs[(size_t)S_ * 32];                 //  256 KB sin table
__device__ short  g_qb[(size_t)B_ * NH_  * S_ * HD_];    //  8.4 MB bf16 roped Q, scaled 0.125*log2e
__device__ short  g_kb[(size_t)B_ * NKV_ * S_ * HD_];    //  2.1 MB bf16 roped K [b][kvh][s][d]
__device__ short  g_vt[(size_t)B_ * NKV_ * HD_ * S_];    //  2.1 MB bf16 V^T    [b][kvh][d][s]
__device__ short  g_ao[(size_t)NTOK * NH_ * HD_];        //  8.4 MB bf16 attn out [tok][h*64+d]

static __device__ inline short f2bf(float f) {
  __hip_bfloat16 h = __float2bfloat16(f);     // RNE
  return *reinterpret_cast<short*>(&h);
}
static __device__ inline unsigned pack2(float lo, float hi) {
  return ((unsigned)(unsigned short)f2bf(hi) << 16) | (unsigned)(unsigned short)f2bf(lo);
}

// ---------------------------------------------------------------------------
// fp32 -> bf16 conversion of x and all weights (float4 in, short4 out).
// ---------------------------------------------------------------------------
#define NX4   (NTOK * D_ / 4)                 // 1048576
#define NWQ4  (NH_ * HD_ * D_ / 4)            //  262144
#define NWK4  (NKV_ * HD_ * D_ / 4)           //   65536
#define NWV4  NWK4
#define NWO4  (D_ * NH_ * HD_ / 4)            //  262144
#define NCVT  (NX4 + NWQ4 + NWK4 + NWV4 + NWO4)

__global__ __launch_bounds__(256) void convert_all(const float* __restrict__ x,
                                                   const float* __restrict__ wq,
                                                   const float* __restrict__ wk,
                                                   const float* __restrict__ wv,
                                                   const float* __restrict__ wo) {
  int i = blockIdx.x * blockDim.x + threadIdx.x;
  if (i >= NCVT) return;
  const float* src; short* dst; int off;
  if (i < NX4)                          { src = x;  dst = g_xb;   off = i; }
  else if (i < NX4 + NWQ4)              { src = wq; dst = g_wqkv; off = i - NX4; }
  else if (i < NX4 + NWQ4 + NWK4)       { src = wk; dst = g_wqkv + (size_t)NWQ4 * 4;          off = i - NX4 - NWQ4; }
  else if (i < NX4 + NWQ4 + NWK4 + NWV4){ src = wv; dst = g_wqkv + (size_t)(NWQ4 + NWK4) * 4; off = i - NX4 - NWQ4 - NWK4; }
  else                                  { src = wo; dst = g_wob;  off = i - NX4 - NWQ4 - NWK4 - NWV4; }
  float4 v = ((const float4*)src)[off];
  short4 s;
  s.x = f2bf(v.x); s.y = f2bf(v.y); s.z = f2bf(v.z); s.w = f2bf(v.w);
  ((short4*)dst)[off] = s;
}

// RoPE cos/sin table: g_rc/g_rs[s*32 + d], accurate sincos once.
__global__ __launch_bounds__(256) void rope_tbl() {
  int i = blockIdx.x * blockDim.x + threadIdx.x;   // 0..65535
  if (i >= S_ * 32) return;
  const int d = i & 31, s = i >> 5;
  const float inv = exp2f((float)d * (-13.287712379549449f / 32.0f));
  const float ang = (float)s * inv;
  float sn, cs;
  sincosf(ang, &sn, &cs);
  g_rc[i] = cs; g_rs[i] = sn;
}

// ---------------------------------------------------------------------------
// GEMM1 + fused RoPE/scatter epilogue.
// y[4096][1536] = xb @ wqkv^T; each n-block of 64 = exactly one head.
//   nb 0..15  -> Q head nb   : rope, scale by 0.125*log2e, -> g_qb[b][h][s][d]
//   nb 16..19 -> K kvh nb-16 : rope,                        -> g_kb[b][kvh][s][d]
//   nb 20..23 -> V kvh nb-20 : transpose,                   -> g_vt[b][kvh][d][s]
// ---------------------------------------------------------------------------
__global__ __launch_bounds__(256) void gemm_qkv_rope() {
  const int w = threadIdx.x >> 6, lane = threadIdx.x & 63;
  const int m0 = blockIdx.x * 128 + w * 32;
  const int nb = blockIdx.y;
  const int n0 = nb * 64;
  const int lr = lane & 15, lk = (lane >> 4) * 8;

  f32x4 acc[2][4] = {};
  for (int k0 = 0; k0 < D_; k0 += 32) {
    short8 a0 = *(const short8*)(g_xb + (size_t)(m0 + lr) * D_ + k0 + lk);
    short8 a1 = *(const short8*)(g_xb + (size_t)(m0 + 16 + lr) * D_ + k0 + lk);
#pragma unroll
    for (int bj = 0; bj < 4; ++bj) {
      short8 bf = *(const short8*)(g_wqkv + (size_t)(n0 + bj * 16 + lr) * D_ + k0 + lk);
      acc[0][bj] = __builtin_amdgcn_mfma_f32_16x16x32_bf16(a0, bf, acc[0][bj], 0, 0, 0);
      acc[1][bj] = __builtin_amdgcn_mfma_f32_16x16x32_bf16(a1, bf, acc[1][bj], 0, 0, 0);
    }
  }
  const int rb = (lane >> 4) * 4;

  if (nb < 20) {
    // Q or K: rope pairs (d0, d0+32) = (acc[af][bj], acc[af][bj+2]), bj in {0,1}
    const float sc = (nb < 16) ? 0.125f * LOG2E : 1.0f;
    short* const base = (nb < 16) ? g_qb : g_kb;
    const int hh = (nb < 16) ? nb : (nb - 16);
    const int nhh = (nb < 16) ? NH_ : NKV_;
#pragma unroll
    for (int af = 0; af < 2; ++af)
#pragma unroll
      for (int bj = 0; bj < 2; ++bj) {
        const int d0 = bj * 16 + lr;
#pragma unroll
        for (int r = 0; r < 4; ++r) {
          const int tok = m0 + af * 16 + rb + r;
          const int bI = tok >> 11, s = tok & (S_ - 1);
          const float c  = g_rc[s * 32 + d0];
          const float sn = g_rs[s * 32 + d0];
          const float lo = acc[af][bj][r], hi = acc[af][bj + 2][r];
          short* dp = base + (((size_t)(bI * nhh + hh)) * S_ + s) * HD_;
          dp[d0]      = f2bf((lo * c - hi * sn) * sc);
          dp[d0 + 32] = f2bf((hi * c + lo * sn) * sc);
        }
      }
  } else {
    // V: transposed store, 4 consecutive s per frag -> short4
    const int kvh = nb - 20;
#pragma unroll
    for (int af = 0; af < 2; ++af)
#pragma unroll
      for (int bj = 0; bj < 4; ++bj) {
        const int d = bj * 16 + lr;
        const int tok0 = m0 + af * 16 + rb;
        const int bI = tok0 >> 11, s0 = tok0 & (S_ - 1);
        short4 s4;
        s4.x = f2bf(acc[af][bj][0]); s4.y = f2bf(acc[af][bj][1]);
        s4.z = f2bf(acc[af][bj][2]); s4.w = f2bf(acc[af][bj][3]);
        *(short4*)(g_vt + (((size_t)(bI * NKV_ + kvh)) * HD_ + d) * S_ + s0) = s4;
      }
  }
}

// ---------------------------------------------------------------------------
// MFMA flash attention, causal, GQA. One wave (64 thr) per block = 16 q rows.
// Swapped QK^T: St = mfma(K, Q) -> St[kv][q], lane holds column q = lane&15.
// Softmax in base-2 (log2e folded into Q). Defer-max (THR=8) makes the
// cross-lane max reduction rare; l kept as per-lane partial, reduced once.
// P^T rebuilt with 8 packed-u32 shfls. PV: O^T = mfma(V^T, P^T).
// ---------------------------------------------------------------------------
__global__ __launch_bounds__(64) void attn_mfma() {
  const int bh  = blockIdx.x;                  // 0..31
  const int b   = bh >> 4, h = bh & 15;
  const int kvh = h >> 2;                      // REP = 4
  const int qw  = (int)(gridDim.y - 1 - blockIdx.y);   // heavy waves dispatch first
  const int lane = threadIdx.x;
  const int g = lane >> 4, l = lane & 15;
  const int q0 = qw * 16;
  const int q_glob = q0 + l;

  const short* Qb = g_qb + ((size_t)bh * S_ + q0) * HD_;
  const short* Kb = g_kb + ((size_t)(b * NKV_ + kvh)) * S_ * HD_;
  const short* Vt = g_vt + ((size_t)(b * NKV_ + kvh)) * HD_ * S_;

  short8 qf[2];
  qf[0] = *(const short8*)(Qb + l * HD_ + g * 8);
  qf[1] = *(const short8*)(Qb + l * HD_ + 32 + g * 8);

  f32x4 o[4] = {};                             // O^T acc: d = df*16 + g*4 + r, q = l
  float m_run = -1e30f, l_part = 0.0f;         // m per-column (uniform in l-group); l per-lane partial

  const int nt = (q0 >> 5) + 1;                // kv tiles of 32
  for (int t = 0; t < nt; ++t) {
    // ---- prefetch K and V fragments (L2-resident)
    const short* Kt = Kb + (size_t)(t * 32) * HD_;
    short8 kf0 = *(const short8*)(Kt + l * HD_ + g * 8);
    short8 kf1 = *(const short8*)(Kt + (16 + l) * HD_ + g * 8);
    short8 kf2 = *(const short8*)(Kt + l * HD_ + 32 + g * 8);
    short8 kf3 = *(const short8*)(Kt + (16 + l) * HD_ + 32 + g * 8);
    short8 vf[4];
#pragma unroll
    for (int df = 0; df < 4; ++df)
      vf[df] = *(const short8*)(Vt + (size_t)(df * 16 + l) * S_ + t * 32 + g * 8);

    // ---- QK^T (swapped): St[kv][q]
    f32x4 st[2] = {};
    st[0] = __builtin_amdgcn_mfma_f32_16x16x32_bf16(kf0, qf[0], st[0], 0, 0, 0);
    st[1] = __builtin_amdgcn_mfma_f32_16x16x32_bf16(kf1, qf[0], st[1], 0, 0, 0);
    st[0] = __builtin_amdgcn_mfma_f32_16x16x32_bf16(kf2, qf[1], st[0], 0, 0, 0);
    st[1] = __builtin_amdgcn_mfma_f32_16x16x32_bf16(kf3, qf[1], st[1], 0, 0, 0);

    // ---- mask + per-lane max (8 scores of column q = l)
    float sv[2][4];
    float mt = -1e30f;
#pragma unroll
    for (int mf = 0; mf < 2; ++mf)
#pragma unroll
      for (int r = 0; r < 4; ++r) {
        const int kv = t * 32 + mf * 16 + g * 4 + r;
        float s = st[mf][r];
        s = (kv > q_glob) ? -1e30f : s;
        sv[mf][r] = s;
        mt = fmaxf(mt, s);
      }
    // ---- defer-max: rescale only when some column's max grew by > 8 (log2)
    if (__any(mt > m_run + 8.0f)) {
      float mr = mt;
      mr = fmaxf(mr, __shfl_xor(mr, 16, 64));
      mr = fmaxf(mr, __shfl_xor(mr, 32, 64));   // per-column max, uniform in l-group
      const float m_new = fmaxf(m_run, mr);
      const float alpha = exp2f(m_run - m_new);
      l_part *= alpha;
#pragma unroll
      for (int df = 0; df < 4; ++df)
#pragma unroll
        for (int r = 0; r < 4; ++r) o[df][r] *= alpha;
      m_run = m_new;
    }
    // ---- P = exp2(S - m), per-lane partial l
    float p[2][4];
#pragma unroll
    for (int mf = 0; mf < 2; ++mf)
#pragma unroll
      for (int r = 0; r < 4; ++r) {
        const float pv = exp2f(sv[mf][r] - m_run);
        p[mf][r] = pv;
        l_part += pv;
      }
    // ---- pack to bf16x2 and redistribute into B-frag with 8 shfls
    unsigned u0 = pack2(p[0][0], p[0][1]);     // kv 4g+0,1
    unsigned u1 = pack2(p[0][2], p[0][3]);     // kv 4g+2,3
    unsigned u2 = pack2(p[1][0], p[1][1]);     // kv 16+4g+0,1
    unsigned u3 = pack2(p[1][2], p[1][3]);     // kv 16+4g+2,3
    const int srcA = ((g & 1) << 5) + l;
    const int srcB = srcA + 16;
    const unsigned a0 = __shfl(u0, srcA, 64), a2 = __shfl(u2, srcA, 64);
    const unsigned b1 = __shfl(u1, srcA, 64), b3 = __shfl(u3, srcA, 64);
    const unsigned c0 = __shfl(u0, srcB, 64), c2 = __shfl(u2, srcB, 64);
    const unsigned d1 = __shfl(u1, srcB, 64), d3 = __shfl(u3, srcB, 64);
    const bool hi = (g & 2);
    unsigned W[4];
    W[0] = hi ? a2 : a0;  W[1] = hi ? b3 : b1;
    W[2] = hi ? c2 : c0;  W[3] = hi ? d3 : d1;
    short8 pt = *reinterpret_cast<short8*>(W);

    // ---- PV: O^T += V^T @ P^T
#pragma unroll
    for (int df = 0; df < 4; ++df)
      o[df] = __builtin_amdgcn_mfma_f32_16x16x32_bf16(vf[df], pt, o[df], 0, 0, 0);
  }

  // final cross-group l reduction (once per wave)
  float l1 = l_part + __shfl_xor(l_part, 16, 64);
  const float l_tot = l1 + __shfl_xor(l1, 32, 64);
  const float inv_l = 1.0f / l_tot;

  short* optr = g_ao + ((size_t)(b * S_ + q_glob)) * (NH_ * HD_) + h * HD_;
#pragma unroll
  for (int df = 0; df < 4; ++df) {
    short4 s4;
    s4.x = f2bf(o[df][0] * inv_l);
    s4.y = f2bf(o[df][1] * inv_l);
    s4.z = f2bf(o[df][2] * inv_l);
    s4.w = f2bf(o[df][3] * inv_l);
    *(short4*)(optr + df * 16 + g * 4) = s4;
  }
}

// ---------------------------------------------------------------------------
// GEMM2: out[4096][1024] = g_ao[4096][1024] @ wob[1024][1024]^T, fp32 out
// ---------------------------------------------------------------------------
__global__ __launch_bounds__(256) void gemm_out(float* __restrict__ out) {
  const int w = threadIdx.x >> 6, lane = threadIdx.x & 63;
  const int m0 = blockIdx.x * 128 + w * 32;
  const int n0 = blockIdx.y * 64;
  const int lr = lane & 15, lk = (lane >> 4) * 8;
  const int K = NH_ * HD_;               // 1024

  f32x4 acc[2][4] = {};
  for (int k0 = 0; k0 < K; k0 += 32) {
    short8 a0 = *(const short8*)(g_ao + (size_t)(m0 + lr) * K + k0 + lk);
    short8 a1 = *(const short8*)(g_ao + (size_t)(m0 + 16 + lr) * K + k0 + lk);
#pragma unroll
    for (int bj = 0; bj < 4; ++bj) {
      short8 bf = *(const short8*)(g_wob + (size_t)(n0 + bj * 16 + lr) * K + k0 + lk);
      acc[0][bj] = __builtin_amdgcn_mfma_f32_16x16x32_bf16(a0, bf, acc[0][bj], 0, 0, 0);
      acc[1][bj] = __builtin_amdgcn_mfma_f32_16x16x32_bf16(a1, bf, acc[1][bj], 0, 0, 0);
    }
  }
  const int rb = (lane >> 4) * 4;
#pragma unroll
  for (int af = 0; af < 2; ++af)
#pragma unroll
    for (int bj = 0; bj < 4; ++bj)
#pragma unroll
      for (int r = 0; r < 4; ++r)
        out[(size_t)(m0 + af * 16 + rb + r) * D_ + n0 + bj * 16 + lr] =
            acc[af][bj][r];
}

// ---------------------------------------------------------------------------
extern "C" void kernel_launch(void* const* d_in, const int* in_sizes, int n_in,
                              void* d_out, int out_size, void* d_ws, size_t ws_size,
                              hipStream_t stream) {
  const float* x  = (const float*)d_in[0];   // float32 per reference
  const float* Wq = (const float*)d_in[1];
  const float* Wk = (const float*)d_in[2];
  const float* Wv = (const float*)d_in[3];
  const float* Wo = (const float*)d_in[4];
  float* out = (float*)d_out;

  convert_all<<<(NCVT + 255) / 256, 256, 0, stream>>>(x, Wq, Wk, Wv, Wo);
  rope_tbl<<<(S_ * 32 + 255) / 256, 256, 0, stream>>>();
  {
    dim3 g(NTOK / 128, QKVN / 64);            // 32 x 24
    gemm_qkv_rope<<<g, 256, 0, stream>>>();
  }
  {
    dim3 g(B_ * NH_, S_ / 16);                // 32 bh x 128 q-waves, 1 wave each
    attn_mfma<<<g, 64, 0, stream>>>();
  }
  {
    dim3 g(NTOK / 128, D_ / 64);              // 32 x 16
    gemm_out<<<g, 256, 0, stream>>>(out);
  }
}

// Round 7
// 322.886 us; speedup vs baseline: 4.3597x; 1.0131x over previous
//
#include <hip/hip_runtime.h>
#include <hip/hip_bf16.h>
#include <math.h>

// Problem constants
#define B_    2
#define S_    2048
#define D_    1024
#define NH_   16
#define NKV_  4
#define HD_   64
#define NTOK  (B_ * S_)                       // 4096
#define QKVN  (NH_ * HD_ + 2 * NKV_ * HD_)    // 1536
#define REP   (NH_ / NKV_)                    // 4

#define LOG2E 1.4426950408889634f

typedef __attribute__((ext_vector_type(8))) short short8;   // 8 bf16 (4 VGPRs), MFMA A/B frag
typedef __attribute__((ext_vector_type(4))) float f32x4;    // MFMA C/D frag

// Static device scratch, all fully rewritten each call.
__device__ short  g_xb[(size_t)NTOK * D_];               //  8.4 MB bf16 x
__device__ short  g_wqkv[(size_t)QKVN * D_];             //  3.1 MB bf16 [Wq;Wk;Wv]
__device__ short  g_wob[(size_t)D_ * NH_ * HD_];         //  2.1 MB bf16 Wo
__device__ float  g_rc[(size_t)S_ * 32];                 //  256 KB cos table [s][d<32]
__device__ float  g_rs[(size_t)S_ * 32];                 //  256 KB sin table
__device__ short  g_qb[(size_t)B_ * NH_  * S_ * HD_];    //  8.4 MB bf16 roped Q, scaled 0.125*log2e
__device__ short  g_kb[(size_t)B_ * NKV_ * S_ * HD_];    //  2.1 MB bf16 roped K [b][kvh][s][d]
__device__ short  g_vt[(size_t)B_ * NKV_ * HD_ * S_];    //  2.1 MB bf16 V^T    [b][kvh][d][s]
__device__ short  g_ao[(size_t)NTOK * NH_ * HD_];        //  8.4 MB bf16 attn out [tok][h*64+d]

static __device__ inline short f2bf(float f) {
  __hip_bfloat16 h = __float2bfloat16(f);     // RNE
  return *reinterpret_cast<short*>(&h);
}
static __device__ inline unsigned pack2(float lo, float hi) {
  return ((unsigned)(unsigned short)f2bf(hi) << 16) | (unsigned)(unsigned short)f2bf(lo);
}

// ---------------------------------------------------------------------------
// fp32 -> bf16 conversion of x and all weights (float4 in, short4 out).
// ---------------------------------------------------------------------------
#define NX4   (NTOK * D_ / 4)                 // 1048576
#define NWQ4  (NH_ * HD_ * D_ / 4)            //  262144
#define NWK4  (NKV_ * HD_ * D_ / 4)           //   65536
#define NWV4  NWK4
#define NWO4  (D_ * NH_ * HD_ / 4)            //  262144
#define NCVT  (NX4 + NWQ4 + NWK4 + NWV4 + NWO4)

__global__ __launch_bounds__(256) void convert_all(const float* __restrict__ x,
                                                   const float* __restrict__ wq,
                                                   const float* __restrict__ wk,
                                                   const float* __restrict__ wv,
                                                   const float* __restrict__ wo) {
  int i = blockIdx.x * blockDim.x + threadIdx.x;
  if (i >= NCVT) return;
  const float* src; short* dst; int off;
  if (i < NX4)                          { src = x;  dst = g_xb;   off = i; }
  else if (i < NX4 + NWQ4)              { src = wq; dst = g_wqkv; off = i - NX4; }
  else if (i < NX4 + NWQ4 + NWK4)       { src = wk; dst = g_wqkv + (size_t)NWQ4 * 4;          off = i - NX4 - NWQ4; }
  else if (i < NX4 + NWQ4 + NWK4 + NWV4){ src = wv; dst = g_wqkv + (size_t)(NWQ4 + NWK4) * 4; off = i - NX4 - NWQ4 - NWK4; }
  else                                  { src = wo; dst = g_wob;  off = i - NX4 - NWQ4 - NWK4 - NWV4; }
  float4 v = ((const float4*)src)[off];
  short4 s;
  s.x = f2bf(v.x); s.y = f2bf(v.y); s.z = f2bf(v.z); s.w = f2bf(v.w);
  ((short4*)dst)[off] = s;
}

// RoPE cos/sin table: g_rc/g_rs[s*32 + d], accurate sincos once.
__global__ __launch_bounds__(256) void rope_tbl() {
  int i = blockIdx.x * blockDim.x + threadIdx.x;   // 0..65535
  if (i >= S_ * 32) return;
  const int d = i & 31, s = i >> 5;
  const float inv = exp2f((float)d * (-13.287712379549449f / 32.0f));
  const float ang = (float)s * inv;
  float sn, cs;
  sincosf(ang, &sn, &cs);
  g_rc[i] = cs; g_rs[i] = sn;
}

// ---------------------------------------------------------------------------
// GEMM1 + fused RoPE/scatter epilogue.
//   nb 0..15  -> Q head nb   : rope, scale by 0.125*log2e, -> g_qb[b][h][s][d]
//   nb 16..19 -> K kvh nb-16 : rope,                        -> g_kb[b][kvh][s][d]
//   nb 20..23 -> V kvh nb-20 : transpose,                   -> g_vt[b][kvh][d][s]
// ---------------------------------------------------------------------------
__global__ __launch_bounds__(256) void gemm_qkv_rope() {
  const int w = threadIdx.x >> 6, lane = threadIdx.x & 63;
  const int m0 = blockIdx.x * 128 + w * 32;
  const int nb = blockIdx.y;
  const int n0 = nb * 64;
  const int lr = lane & 15, lk = (lane >> 4) * 8;

  f32x4 acc[2][4] = {};
  for (int k0 = 0; k0 < D_; k0 += 32) {
    short8 a0 = *(const short8*)(g_xb + (size_t)(m0 + lr) * D_ + k0 + lk);
    short8 a1 = *(const short8*)(g_xb + (size_t)(m0 + 16 + lr) * D_ + k0 + lk);
#pragma unroll
    for (int bj = 0; bj < 4; ++bj) {
      short8 bf = *(const short8*)(g_wqkv + (size_t)(n0 + bj * 16 + lr) * D_ + k0 + lk);
      acc[0][bj] = __builtin_amdgcn_mfma_f32_16x16x32_bf16(a0, bf, acc[0][bj], 0, 0, 0);
      acc[1][bj] = __builtin_amdgcn_mfma_f32_16x16x32_bf16(a1, bf, acc[1][bj], 0, 0, 0);
    }
  }
  const int rb = (lane >> 4) * 4;

  if (nb < 20) {
    const float sc = (nb < 16) ? 0.125f * LOG2E : 1.0f;
    short* const base = (nb < 16) ? g_qb : g_kb;
    const int hh = (nb < 16) ? nb : (nb - 16);
    const int nhh = (nb < 16) ? NH_ : NKV_;
#pragma unroll
    for (int af = 0; af < 2; ++af)
#pragma unroll
      for (int bj = 0; bj < 2; ++bj) {
        const int d0 = bj * 16 + lr;
#pragma unroll
        for (int r = 0; r < 4; ++r) {
          const int tok = m0 + af * 16 + rb + r;
          const int bI = tok >> 11, s = tok & (S_ - 1);
          const float c  = g_rc[s * 32 + d0];
          const float sn = g_rs[s * 32 + d0];
          const float lo = acc[af][bj][r], hi = acc[af][bj + 2][r];
          short* dp = base + (((size_t)(bI * nhh + hh)) * S_ + s) * HD_;
          dp[d0]      = f2bf((lo * c - hi * sn) * sc);
          dp[d0 + 32] = f2bf((hi * c + lo * sn) * sc);
        }
      }
  } else {
    const int kvh = nb - 20;
#pragma unroll
    for (int af = 0; af < 2; ++af)
#pragma unroll
      for (int bj = 0; bj < 4; ++bj) {
        const int d = bj * 16 + lr;
        const int tok0 = m0 + af * 16 + rb;
        const int bI = tok0 >> 11, s0 = tok0 & (S_ - 1);
        short4 s4;
        s4.x = f2bf(acc[af][bj][0]); s4.y = f2bf(acc[af][bj][1]);
        s4.z = f2bf(acc[af][bj][2]); s4.w = f2bf(acc[af][bj][3]);
        *(short4*)(g_vt + (((size_t)(bI * NKV_ + kvh)) * HD_ + d) * S_ + s0) = s4;
      }
  }
}

// ---------------------------------------------------------------------------
// MFMA flash attention, causal, GQA — SPLIT-KV over 4 waves per block.
// Block = 256 thr = 4 waves, all on the same 16 q rows (q0 = qw*16).
// Wave w handles kv tiles t = w, w+4, ... (tiles of 32 kv); per-tile body is
// the verified round-5 code (swapped QK^T, defer-max base-2 softmax, 8 packed
// shfls for P^T, PV via V^T). Final merge of (m, l, O) across waves in LDS.
// ---------------------------------------------------------------------------
__global__ __launch_bounds__(256) void attn_mfma() {
  const int bh  = blockIdx.x;                  // 0..31
  const int b   = bh >> 4, h = bh & 15;
  const int kvh = h >> 2;                      // REP = 4
  const int qw  = (int)(gridDim.y - 1 - blockIdx.y);   // heavy blocks dispatch first
  const int w   = threadIdx.x >> 6;            // wave 0..3
  const int lane = threadIdx.x & 63;
  const int g = lane >> 4, l = lane & 15;
  const int q0 = qw * 16;
  const int q_glob = q0 + l;

  const short* Qb = g_qb + ((size_t)bh * S_ + q0) * HD_;
  const short* Kb = g_kb + ((size_t)(b * NKV_ + kvh)) * S_ * HD_;
  const short* Vt = g_vt + ((size_t)(b * NKV_ + kvh)) * HD_ * S_;

  short8 qf[2];
  qf[0] = *(const short8*)(Qb + l * HD_ + g * 8);
  qf[1] = *(const short8*)(Qb + l * HD_ + 32 + g * 8);

  f32x4 o[4] = {};                             // O^T acc: d = df*16 + g*4 + r, q = l
  float m_run = -1e30f, l_part = 0.0f;

  const int nt = (q0 >> 5) + 1;                // kv tiles of 32
  for (int t = w; t < nt; t += 4) {
    // ---- prefetch K and V fragments (L2-resident)
    const short* Kt = Kb + (size_t)(t * 32) * HD_;
    short8 kf0 = *(const short8*)(Kt + l * HD_ + g * 8);
    short8 kf1 = *(const short8*)(Kt + (16 + l) * HD_ + g * 8);
    short8 kf2 = *(const short8*)(Kt + l * HD_ + 32 + g * 8);
    short8 kf3 = *(const short8*)(Kt + (16 + l) * HD_ + 32 + g * 8);
    short8 vf[4];
#pragma unroll
    for (int df = 0; df < 4; ++df)
      vf[df] = *(const short8*)(Vt + (size_t)(df * 16 + l) * S_ + t * 32 + g * 8);

    // ---- QK^T (swapped): St[kv][q]
    f32x4 st[2] = {};
    st[0] = __builtin_amdgcn_mfma_f32_16x16x32_bf16(kf0, qf[0], st[0], 0, 0, 0);
    st[1] = __builtin_amdgcn_mfma_f32_16x16x32_bf16(kf1, qf[0], st[1], 0, 0, 0);
    st[0] = __builtin_amdgcn_mfma_f32_16x16x32_bf16(kf2, qf[1], st[0], 0, 0, 0);
    st[1] = __builtin_amdgcn_mfma_f32_16x16x32_bf16(kf3, qf[1], st[1], 0, 0, 0);

    // ---- mask + per-lane max (8 scores of column q = l)
    float sv[2][4];
    float mt = -1e30f;
#pragma unroll
    for (int mf = 0; mf < 2; ++mf)
#pragma unroll
      for (int r = 0; r < 4; ++r) {
        const int kv = t * 32 + mf * 16 + g * 4 + r;
        float s = st[mf][r];
        s = (kv > q_glob) ? -1e30f : s;
        sv[mf][r] = s;
        mt = fmaxf(mt, s);
      }
    // ---- defer-max: rescale only when some column's max grew by > 8 (log2)
    if (__any(mt > m_run + 8.0f)) {
      float mr = mt;
      mr = fmaxf(mr, __shfl_xor(mr, 16, 64));
      mr = fmaxf(mr, __shfl_xor(mr, 32, 64));   // per-column max, uniform over g
      const float m_new = fmaxf(m_run, mr);
      const float alpha = exp2f(m_run - m_new);
      l_part *= alpha;
#pragma unroll
      for (int df = 0; df < 4; ++df)
#pragma unroll
        for (int r = 0; r < 4; ++r) o[df][r] *= alpha;
      m_run = m_new;
    }
    // ---- P = exp2(S - m), per-lane partial l
    float p[2][4];
#pragma unroll
    for (int mf = 0; mf < 2; ++mf)
#pragma unroll
      for (int r = 0; r < 4; ++r) {
        const float pv = exp2f(sv[mf][r] - m_run);
        p[mf][r] = pv;
        l_part += pv;
      }
    // ---- pack to bf16x2 and redistribute into B-frag with 8 shfls
    unsigned u0 = pack2(p[0][0], p[0][1]);
    unsigned u1 = pack2(p[0][2], p[0][3]);
    unsigned u2 = pack2(p[1][0], p[1][1]);
    unsigned u3 = pack2(p[1][2], p[1][3]);
    const int srcA = ((g & 1) << 5) + l;
    const int srcB = srcA + 16;
    const unsigned a0 = __shfl(u0, srcA, 64), a2 = __shfl(u2, srcA, 64);
    const unsigned b1 = __shfl(u1, srcA, 64), b3 = __shfl(u3, srcA, 64);
    const unsigned c0 = __shfl(u0, srcB, 64), c2 = __shfl(u2, srcB, 64);
    const unsigned d1 = __shfl(u1, srcB, 64), d3 = __shfl(u3, srcB, 64);
    const bool hi = (g & 2);
    unsigned W[4];
    W[0] = hi ? a2 : a0;  W[1] = hi ? b3 : b1;
    W[2] = hi ? c2 : c0;  W[3] = hi ? d3 : d1;
    short8 pt = *reinterpret_cast<short8*>(W);

    // ---- PV: O^T += V^T @ P^T
#pragma unroll
    for (int df = 0; df < 4; ++df)
      o[df] = __builtin_amdgcn_mfma_f32_16x16x32_bf16(vf[df], pt, o[df], 0, 0, 0);
  }

  // ---- per-wave l reduction over g-groups (uniform per column afterwards)
  float l1 = l_part + __shfl_xor(l_part, 16, 64);
  const float l_tot = l1 + __shfl_xor(l1, 32, 64);

  // ---- cross-wave merge via LDS
  __shared__ float lds_m[4][16];
  __shared__ float lds_l[4][16];
  __shared__ float lds_o[4][16][68];           // [wave][q][d], +4 pad vs 16-way conflict
  if (g == 0) { lds_m[w][l] = m_run; lds_l[w][l] = l_tot; }
#pragma unroll
  for (int df = 0; df < 4; ++df)
#pragma unroll
    for (int r = 0; r < 4; ++r)
      lds_o[w][l][df * 16 + g * 4 + r] = o[df][r];
  __syncthreads();

  // 256 threads: q = tid&15, d-group = tid>>4 (4 floats each)
  const int tid = threadIdx.x;
  const int q = tid & 15, dg = tid >> 4;
  float ms = lds_m[0][q];
#pragma unroll
  for (int w2 = 1; w2 < 4; ++w2) ms = fmaxf(ms, lds_m[w2][q]);
  float lsum = 0.0f;
  float od[4] = {0.0f, 0.0f, 0.0f, 0.0f};
#pragma unroll
  for (int w2 = 0; w2 < 4; ++w2) {
    const float sc = exp2f(lds_m[w2][q] - ms);   // 0 for empty waves
    lsum += lds_l[w2][q] * sc;
#pragma unroll
    for (int j = 0; j < 4; ++j) od[j] += sc * lds_o[w2][q][dg * 4 + j];
  }
  const float inv_l = 1.0f / lsum;
  short* optr = g_ao + ((size_t)(b * S_ + q0 + q)) * (NH_ * HD_) + h * HD_;
  short4 s4;
  s4.x = f2bf(od[0] * inv_l);
  s4.y = f2bf(od[1] * inv_l);
  s4.z = f2bf(od[2] * inv_l);
  s4.w = f2bf(od[3] * inv_l);
  *(short4*)(optr + dg * 4) = s4;
}

// ---------------------------------------------------------------------------
// GEMM2: out[4096][1024] = g_ao[4096][1024] @ wob[1024][1024]^T, fp32 out
// ---------------------------------------------------------------------------
__global__ __launch_bounds__(256) void gemm_out(float* __restrict__ out) {
  const int w = threadIdx.x >> 6, lane = threadIdx.x & 63;
  const int m0 = blockIdx.x * 128 + w * 32;
  const int n0 = blockIdx.y * 64;
  const int lr = lane & 15, lk = (lane >> 4) * 8;
  const int K = NH_ * HD_;               // 1024

  f32x4 acc[2][4] = {};
  for (int k0 = 0; k0 < K; k0 += 32) {
    short8 a0 = *(const short8*)(g_ao + (size_t)(m0 + lr) * K + k0 + lk);
    short8 a1 = *(const short8*)(g_ao + (size_t)(m0 + 16 + lr) * K + k0 + lk);
#pragma unroll
    for (int bj = 0; bj < 4; ++bj) {
      short8 bf = *(const short8*)(g_wob + (size_t)(n0 + bj * 16 + lr) * K + k0 + lk);
      acc[0][bj] = __builtin_amdgcn_mfma_f32_16x16x32_bf16(a0, bf, acc[0][bj], 0, 0, 0);
      acc[1][bj] = __builtin_amdgcn_mfma_f32_16x16x32_bf16(a1, bf, acc[1][bj], 0, 0, 0);
    }
  }
  const int rb = (lane >> 4) * 4;
#pragma unroll
  for (int af = 0; af < 2; ++af)
#pragma unroll
    for (int bj = 0; bj < 4; ++bj)
#pragma unroll
      for (int r = 0; r < 4; ++r)
        out[(size_t)(m0 + af * 16 + rb + r) * D_ + n0 + bj * 16 + lr] =
            acc[af][bj][r];
}

// ---------------------------------------------------------------------------
extern "C" void kernel_launch(void* const* d_in, const int* in_sizes, int n_in,
                              void* d_out, int out_size, void* d_ws, size_t ws_size,
                              hipStream_t stream) {
  const float* x  = (const float*)d_in[0];   // float32 per reference
  const float* Wq = (const float*)d_in[1];
  const float* Wk = (const float*)d_in[2];
  const float* Wv = (const float*)d_in[3];
  const float* Wo = (const float*)d_in[4];
  float* out = (float*)d_out;

  convert_all<<<(NCVT + 255) / 256, 256, 0, stream>>>(x, Wq, Wk, Wv, Wo);
  rope_tbl<<<(S_ * 32 + 255) / 256, 256, 0, stream>>>();
  {
    dim3 g(NTOK / 128, QKVN / 64);            // 32 x 24
    gemm_qkv_rope<<<g, 256, 0, stream>>>();
  }
  {
    dim3 g(B_ * NH_, S_ / 16);                // 32 bh x 128 q-blocks, 4 waves each
    attn_mfma<<<g, 256, 0, stream>>>();
  }
  {
    dim3 g(NTOK / 128, D_ / 64);              // 32 x 16
    gemm_out<<<g, 256, 0, stream>>>(out);
  }
}

// Round 9
// 295.400 us; speedup vs baseline: 4.7654x; 1.0930x over previous
//
#include <hip/hip_runtime.h>
#include <hip/hip_bf16.h>
#include <math.h>

// Problem constants
#define B_    2
#define S_    2048
#define D_    1024
#define NH_   16
#define NKV_  4
#define HD_   64
#define NTOK  (B_ * S_)                       // 4096
#define QKVN  (NH_ * HD_ + 2 * NKV_ * HD_)    // 1536
#define REP   (NH_ / NKV_)                    // 4

#define LOG2E 1.4426950408889634f

typedef __attribute__((ext_vector_type(8))) short short8;   // 8 bf16 (4 VGPRs)
typedef __attribute__((ext_vector_type(4))) short short4v;  // 4 bf16 (2 VGPRs)
typedef __attribute__((ext_vector_type(4))) float f32x4;    // MFMA C/D frag

// K=16 bf16 MFMA: builtin if present, else raw asm (ISA: v_mfma_f32_16x16x16_bf16)
#if __has_builtin(__builtin_amdgcn_mfma_f32_16x16x16bf16_1k)
#define MFMA16(acc, a, b) acc = __builtin_amdgcn_mfma_f32_16x16x16bf16_1k(a, b, acc, 0, 0, 0)
#else
#define MFMA16(acc, a, b) asm("v_mfma_f32_16x16x16_bf16 %0, %1, %2, %0" : "+v"(acc) : "v"(a), "v"(b))
#endif

// Static device scratch, all fully rewritten each call.
__device__ short  g_xb[(size_t)NTOK * D_];               //  8.4 MB bf16 x
__device__ short  g_wqkv[(size_t)QKVN * D_];             //  3.1 MB bf16 [Wq;Wk;Wv]
__device__ short  g_wob[(size_t)D_ * NH_ * HD_];         //  2.1 MB bf16 Wo
__device__ float  g_rc[(size_t)S_ * 32];                 //  256 KB cos table [s][d<32]
__device__ float  g_rs[(size_t)S_ * 32];                 //  256 KB sin table
__device__ short  g_qb[(size_t)B_ * NH_  * S_ * HD_];    //  8.4 MB bf16 roped Q, scaled 0.125*log2e
__device__ short  g_kb[(size_t)B_ * NKV_ * S_ * HD_];    //  2.1 MB bf16 roped K [b][kvh][s][d]
// V^T in MFMA-A-frag blocked layout: [b][kvh][t=64][half=2][df=4][lane=64] x short4
// element (t,half,df,lane): V^T[d = df*16 + (lane&15)][kv = t*32 + half*16 + 4*(lane>>4) + i]
__device__ short  g_vts[(size_t)B_ * NKV_ * HD_ * S_];   //  2.1 MB
__device__ short  g_ao[(size_t)NTOK * NH_ * HD_];        //  8.4 MB bf16 attn out [tok][h*64+d]

static __device__ inline short f2bf(float f) {
  __hip_bfloat16 h = __float2bfloat16(f);     // RNE
  return *reinterpret_cast<short*>(&h);
}

// ---------------------------------------------------------------------------
// fp32 -> bf16 conversion of x and all weights (float4 in, short4 out).
// ---------------------------------------------------------------------------
#define NX4   (NTOK * D_ / 4)                 // 1048576
#define NWQ4  (NH_ * HD_ * D_ / 4)            //  262144
#define NWK4  (NKV_ * HD_ * D_ / 4)           //   65536
#define NWV4  NWK4
#define NWO4  (D_ * NH_ * HD_ / 4)            //  262144
#define NCVT  (NX4 + NWQ4 + NWK4 + NWV4 + NWO4)

__global__ __launch_bounds__(256) void convert_all(const float* __restrict__ x,
                                                   const float* __restrict__ wq,
                                                   const float* __restrict__ wk,
                                                   const float* __restrict__ wv,
                                                   const float* __restrict__ wo) {
  int i = blockIdx.x * blockDim.x + threadIdx.x;
  if (i >= NCVT) return;
  const float* src; short* dst; int off;
  if (i < NX4)                          { src = x;  dst = g_xb;   off = i; }
  else if (i < NX4 + NWQ4)              { src = wq; dst = g_wqkv; off = i - NX4; }
  else if (i < NX4 + NWQ4 + NWK4)       { src = wk; dst = g_wqkv + (size_t)NWQ4 * 4;          off = i - NX4 - NWQ4; }
  else if (i < NX4 + NWQ4 + NWK4 + NWV4){ src = wv; dst = g_wqkv + (size_t)(NWQ4 + NWK4) * 4; off = i - NX4 - NWQ4 - NWK4; }
  else                                  { src = wo; dst = g_wob;  off = i - NX4 - NWQ4 - NWK4 - NWV4; }
  float4 v = ((const float4*)src)[off];
  short4 s;
  s.x = f2bf(v.x); s.y = f2bf(v.y); s.z = f2bf(v.z); s.w = f2bf(v.w);
  ((short4*)dst)[off] = s;
}

// RoPE cos/sin table: g_rc/g_rs[s*32 + d], accurate sincos once.
__global__ __launch_bounds__(256) void rope_tbl() {
  int i = blockIdx.x * blockDim.x + threadIdx.x;   // 0..65535
  if (i >= S_ * 32) return;
  const int d = i & 31, s = i >> 5;
  const float inv = exp2f((float)d * (-13.287712379549449f / 32.0f));
  const float ang = (float)s * inv;
  float sn, cs;
  sincosf(ang, &sn, &cs);
  g_rc[i] = cs; g_rs[i] = sn;
}

// ---------------------------------------------------------------------------
// GEMM1 + fused RoPE/scatter epilogue.
//   nb 0..15  -> Q head nb   : rope, scale by 0.125*log2e, -> g_qb[b][h][s][d]
//   nb 16..19 -> K kvh nb-16 : rope,                        -> g_kb[b][kvh][s][d]
//   nb 20..23 -> V kvh nb-20 : blocked-transpose,           -> g_vts (A-frag layout)
// ---------------------------------------------------------------------------
__global__ __launch_bounds__(256) void gemm_qkv_rope() {
  const int w = threadIdx.x >> 6, lane = threadIdx.x & 63;
  const int m0 = blockIdx.x * 128 + w * 32;
  const int nb = blockIdx.y;
  const int n0 = nb * 64;
  const int lr = lane & 15, lk = (lane >> 4) * 8;

  f32x4 acc[2][4] = {};
  for (int k0 = 0; k0 < D_; k0 += 32) {
    short8 a0 = *(const short8*)(g_xb + (size_t)(m0 + lr) * D_ + k0 + lk);
    short8 a1 = *(const short8*)(g_xb + (size_t)(m0 + 16 + lr) * D_ + k0 + lk);
#pragma unroll
    for (int bj = 0; bj < 4; ++bj) {
      short8 bf = *(const short8*)(g_wqkv + (size_t)(n0 + bj * 16 + lr) * D_ + k0 + lk);
      acc[0][bj] = __builtin_amdgcn_mfma_f32_16x16x32_bf16(a0, bf, acc[0][bj], 0, 0, 0);
      acc[1][bj] = __builtin_amdgcn_mfma_f32_16x16x32_bf16(a1, bf, acc[1][bj], 0, 0, 0);
    }
  }
  const int rb = (lane >> 4) * 4;

  if (nb < 20) {
    const float sc = (nb < 16) ? 0.125f * LOG2E : 1.0f;
    short* const base = (nb < 16) ? g_qb : g_kb;
    const int hh = (nb < 16) ? nb : (nb - 16);
    const int nhh = (nb < 16) ? NH_ : NKV_;
#pragma unroll
    for (int af = 0; af < 2; ++af)
#pragma unroll
      for (int bj = 0; bj < 2; ++bj) {
        const int d0 = bj * 16 + lr;
#pragma unroll
        for (int r = 0; r < 4; ++r) {
          const int tok = m0 + af * 16 + rb + r;
          const int bI = tok >> 11, s = tok & (S_ - 1);
          const float c  = g_rc[s * 32 + d0];
          const float sn = g_rs[s * 32 + d0];
          const float lo = acc[af][bj][r], hi = acc[af][bj + 2][r];
          short* dp = base + (((size_t)(bI * nhh + hh)) * S_ + s) * HD_;
          dp[d0]      = f2bf((lo * c - hi * sn) * sc);
          dp[d0 + 32] = f2bf((hi * c + lo * sn) * sc);
        }
      }
  } else {
    // V: writer lane (g,l) holds exactly reader lane (g,l)'s A-frag quad:
    //   d = bj*16 + l, kv quad start = 4g within half-tile af of kv-tile m0>>5.
    const int kvh = nb - 20;
#pragma unroll
    for (int af = 0; af < 2; ++af)
#pragma unroll
      for (int bj = 0; bj < 4; ++bj) {
        const int tok0 = m0 + af * 16 + rb;
        const int bI = tok0 >> 11, sl = tok0 & (S_ - 1);
        const int t = sl >> 5;
        const int half = (sl >> 4) & 1;
        short4 s4;
        s4.x = f2bf(acc[af][bj][0]); s4.y = f2bf(acc[af][bj][1]);
        s4.z = f2bf(acc[af][bj][2]); s4.w = f2bf(acc[af][bj][3]);
        *(short4*)(g_vts + ((((size_t)(bI * NKV_ + kvh) * 64 + t) * 2 + half) * 4 + bj) * 256
                         + lane * 4) = s4;
      }
  }
}

// ---------------------------------------------------------------------------
// MFMA flash attention, causal, GQA — SPLIT-KV over 4 waves per block.
// Swapped QK^T (16x16x32): St[kv][q], lane (g,l) holds P[kv=mf*16+4g+r][q=l]
// == EXACTLY the B-frag of a K=16 MFMA. PV = 8x mfma_f32_16x16x16_bf16 with
// V^T A-frags from g_vts: ZERO cross-lane ops. P->bf16 via 4 v_cvt_pk.
// ---------------------------------------------------------------------------
__global__ __launch_bounds__(256) void attn_mfma() {
  const int bh  = blockIdx.x;                  // 0..31
  const int b   = bh >> 4, h = bh & 15;
  const int kvh = h >> 2;                      // REP = 4
  const int qw  = (int)(gridDim.y - 1 - blockIdx.y);   // heavy blocks dispatch first
  const int w   = threadIdx.x >> 6;            // wave 0..3
  const int lane = threadIdx.x & 63;
  const int g = lane >> 4, l = lane & 15;
  const int q0 = qw * 16;
  const int q_glob = q0 + l;

  const short* Qb  = g_qb + ((size_t)bh * S_ + q0) * HD_;
  const short* Kb  = g_kb + ((size_t)(b * NKV_ + kvh)) * S_ * HD_;
  const short* Vts = g_vts + (size_t)(b * NKV_ + kvh) * 64 * 2048 + lane * 4;

  short8 qf[2];
  qf[0] = *(const short8*)(Qb + l * HD_ + g * 8);
  qf[1] = *(const short8*)(Qb + l * HD_ + 32 + g * 8);

  f32x4 o[4] = {};                             // O^T acc: d = df*16 + g*4 + r, q = l
  float m_run = -1e30f, l_part = 0.0f;

  const int nt = (q0 >> 5) + 1;                // kv tiles of 32
  for (int t = w; t < nt; t += 4) {
    // ---- K frags (row-major, full-cacheline) + V A-frags (lane-major, coalesced)
    const short* Kt = Kb + (size_t)(t * 32) * HD_;
    short8 kf0 = *(const short8*)(Kt + l * HD_ + g * 8);
    short8 kf1 = *(const short8*)(Kt + (16 + l) * HD_ + g * 8);
    short8 kf2 = *(const short8*)(Kt + l * HD_ + 32 + g * 8);
    short8 kf3 = *(const short8*)(Kt + (16 + l) * HD_ + 32 + g * 8);
    const short* Vb = Vts + (size_t)t * 2048;
    short4v vfrag[2][4];
#pragma unroll
    for (int mf = 0; mf < 2; ++mf)
#pragma unroll
      for (int df = 0; df < 4; ++df)
        vfrag[mf][df] = *(const short4v*)(Vb + (mf * 4 + df) * 256);

    // ---- QK^T (swapped): St[kv][q]
    f32x4 st[2] = {};
    st[0] = __builtin_amdgcn_mfma_f32_16x16x32_bf16(kf0, qf[0], st[0], 0, 0, 0);
    st[1] = __builtin_amdgcn_mfma_f32_16x16x32_bf16(kf1, qf[0], st[1], 0, 0, 0);
    st[0] = __builtin_amdgcn_mfma_f32_16x16x32_bf16(kf2, qf[1], st[0], 0, 0, 0);
    st[1] = __builtin_amdgcn_mfma_f32_16x16x32_bf16(kf3, qf[1], st[1], 0, 0, 0);

    // ---- mask + per-lane max (8 scores of column q = l)
    float sv[2][4];
    float mt = -1e30f;
#pragma unroll
    for (int mf = 0; mf < 2; ++mf)
#pragma unroll
      for (int r = 0; r < 4; ++r) {
        const int kv = t * 32 + mf * 16 + g * 4 + r;
        float s = st[mf][r];
        s = (kv > q_glob) ? -1e30f : s;
        sv[mf][r] = s;
        mt = fmaxf(mt, s);
      }
    // ---- defer-max: rescale only when some column's max grew by > 8 (log2)
    if (__any(mt > m_run + 8.0f)) {
      float mr = mt;
      mr = fmaxf(mr, __shfl_xor(mr, 16, 64));
      mr = fmaxf(mr, __shfl_xor(mr, 32, 64));   // per-column max, uniform over g
      const float m_new = fmaxf(m_run, mr);
      const float alpha = exp2f(m_run - m_new);
      l_part *= alpha;
#pragma unroll
      for (int df = 0; df < 4; ++df)
#pragma unroll
        for (int r = 0; r < 4; ++r) o[df][r] *= alpha;
      m_run = m_new;
    }
    // ---- P = exp2(S - m); pack in-lane via v_cvt_pk; PV with K=16 MFMAs
#pragma unroll
    for (int mf = 0; mf < 2; ++mf) {
      float p0 = exp2f(sv[mf][0] - m_run);
      float p1 = exp2f(sv[mf][1] - m_run);
      float p2 = exp2f(sv[mf][2] - m_run);
      float p3 = exp2f(sv[mf][3] - m_run);
      l_part += (p0 + p1) + (p2 + p3);
      unsigned ulo, uhi;
      asm("v_cvt_pk_bf16_f32 %0, %1, %2" : "=v"(ulo) : "v"(p0), "v"(p1));
      asm("v_cvt_pk_bf16_f32 %0, %1, %2" : "=v"(uhi) : "v"(p2), "v"(p3));
      unsigned pw[2] = {ulo, uhi};
      short4v pf = *reinterpret_cast<const short4v*>(pw);
#pragma unroll
      for (int df = 0; df < 4; ++df)
        MFMA16(o[df], vfrag[mf][df], pf);
    }
  }

  // ---- per-wave l reduction over g-groups (uniform per column afterwards)
  float l1 = l_part + __shfl_xor(l_part, 16, 64);
  const float l_tot = l1 + __shfl_xor(l1, 32, 64);

  // ---- cross-wave merge via LDS
  __shared__ float lds_m[4][16];
  __shared__ float lds_l[4][16];
  __shared__ float lds_o[4][16][68];           // [wave][q][d], +4 pad vs 16-way conflict
  if (g == 0) { lds_m[w][l] = m_run; lds_l[w][l] = l_tot; }
#pragma unroll
  for (int df = 0; df < 4; ++df)
#pragma unroll
    for (int r = 0; r < 4; ++r)
      lds_o[w][l][df * 16 + g * 4 + r] = o[df][r];
  __syncthreads();

  // 256 threads: q = tid&15, d-group = tid>>4 (4 floats each)
  const int tid = threadIdx.x;
  const int q = tid & 15, dg = tid >> 4;
  float ms = lds_m[0][q];
#pragma unroll
  for (int w2 = 1; w2 < 4; ++w2) ms = fmaxf(ms, lds_m[w2][q]);
  float lsum = 0.0f;
  float od[4] = {0.0f, 0.0f, 0.0f, 0.0f};
#pragma unroll
  for (int w2 = 0; w2 < 4; ++w2) {
    const float sc = exp2f(lds_m[w2][q] - ms);   // 0 for empty waves
    lsum += lds_l[w2][q] * sc;
#pragma unroll
    for (int j = 0; j < 4; ++j) od[j] += sc * lds_o[w2][q][dg * 4 + j];
  }
  const float inv_l = 1.0f / lsum;
  short* optr = g_ao + ((size_t)(b * S_ + q0 + q)) * (NH_ * HD_) + h * HD_;
  short4 s4;
  s4.x = f2bf(od[0] * inv_l);
  s4.y = f2bf(od[1] * inv_l);
  s4.z = f2bf(od[2] * inv_l);
  s4.w = f2bf(od[3] * inv_l);
  *(short4*)(optr + dg * 4) = s4;
}

// ---------------------------------------------------------------------------
// GEMM2: out[4096][1024] = g_ao[4096][1024] @ wob[1024][1024]^T, fp32 out
// ---------------------------------------------------------------------------
__global__ __launch_bounds__(256) void gemm_out(float* __restrict__ out) {
  const int w = threadIdx.x >> 6, lane = threadIdx.x & 63;
  const int m0 = blockIdx.x * 128 + w * 32;
  const int n0 = blockIdx.y * 64;
  const int lr = lane & 15, lk = (lane >> 4) * 8;
  const int K = NH_ * HD_;               // 1024

  f32x4 acc[2][4] = {};
  for (int k0 = 0; k0 < K; k0 += 32) {
    short8 a0 = *(const short8*)(g_ao + (size_t)(m0 + lr) * K + k0 + lk);
    short8 a1 = *(const short8*)(g_ao + (size_t)(m0 + 16 + lr) * K + k0 + lk);
#pragma unroll
    for (int bj = 0; bj < 4; ++bj) {
      short8 bf = *(const short8*)(g_wob + (size_t)(n0 + bj * 16 + lr) * K + k0 + lk);
      acc[0][bj] = __builtin_amdgcn_mfma_f32_16x16x32_bf16(a0, bf, acc[0][bj], 0, 0, 0);
      acc[1][bj] = __builtin_amdgcn_mfma_f32_16x16x32_bf16(a1, bf, acc[1][bj], 0, 0, 0);
    }
  }
  const int rb = (lane >> 4) * 4;
#pragma unroll
  for (int af = 0; af < 2; ++af)
#pragma unroll
    for (int bj = 0; bj < 4; ++bj)
#pragma unroll
      for (int r = 0; r < 4; ++r)
        out[(size_t)(m0 + af * 16 + rb + r) * D_ + n0 + bj * 16 + lr] =
            acc[af][bj][r];
}

// ---------------------------------------------------------------------------
extern "C" void kernel_launch(void* const* d_in, const int* in_sizes, int n_in,
                              void* d_out, int out_size, void* d_ws, size_t ws_size,
                              hipStream_t stream) {
  const float* x  = (const float*)d_in[0];   // float32 per reference
  const float* Wq = (const float*)d_in[1];
  const float* Wk = (const float*)d_in[2];
  const float* Wv = (const float*)d_in[3];
  const float* Wo = (const float*)d_in[4];
  float* out = (float*)d_out;

  convert_all<<<(NCVT + 255) / 256, 256, 0, stream>>>(x, Wq, Wk, Wv, Wo);
  rope_tbl<<<(S_ * 32 + 255) / 256, 256, 0, stream>>>();
  {
    dim3 g(NTOK / 128, QKVN / 64);            // 32 x 24
    gemm_qkv_rope<<<g, 256, 0, stream>>>();
  }
  {
    dim3 g(B_ * NH_, S_ / 16);                // 32 bh x 128 q-blocks, 4 waves each
    attn_mfma<<<g, 256, 0, stream>>>();
  }
  {
    dim3 g(NTOK / 128, D_ / 64);              // 32 x 16
    gemm_out<<<g, 256, 0, stream>>>(out);
  }
}

// Round 12
// 294.157 us; speedup vs baseline: 4.7855x; 1.0042x over previous
//
#include <hip/hip_runtime.h>
#include <hip/hip_bf16.h>
#include <math.h>

// Problem constants
#define B_    2
#define S_    2048
#define D_    1024
#define NH_   16
#define NKV_  4
#define HD_   64
#define NTOK  (B_ * S_)                       // 4096
#define QKVN  (NH_ * HD_ + 2 * NKV_ * HD_)    // 1536
#define REP   (NH_ / NKV_)                    // 4

#define LOG2E 1.4426950408889634f

typedef __attribute__((ext_vector_type(8))) short short8;   // 8 bf16 (4 VGPRs)
typedef __attribute__((ext_vector_type(4))) short short4v;  // 4 bf16 (2 VGPRs)
typedef __attribute__((ext_vector_type(4))) float f32x4;    // MFMA C/D frag

// K=16 bf16 MFMA: builtin if present, else raw asm (ISA: v_mfma_f32_16x16x16_bf16)
#if __has_builtin(__builtin_amdgcn_mfma_f32_16x16x16bf16_1k)
#define MFMA16(acc, a, b) acc = __builtin_amdgcn_mfma_f32_16x16x16bf16_1k(a, b, acc, 0, 0, 0)
#else
#define MFMA16(acc, a, b) asm("v_mfma_f32_16x16x16_bf16 %0, %1, %2, %0" : "+v"(acc) : "v"(a), "v"(b))
#endif

// Static device scratch, all fully rewritten each call.
__device__ short  g_xb[(size_t)NTOK * D_];               //  8.4 MB bf16 x
__device__ short  g_wqkv[(size_t)QKVN * D_];             //  3.1 MB bf16 [Wq;Wk;Wv]
__device__ short  g_wob[(size_t)D_ * NH_ * HD_];         //  2.1 MB bf16 Wo
__device__ float  g_rc[(size_t)S_ * 32];                 //  256 KB cos table [s][d<32]
__device__ float  g_rs[(size_t)S_ * 32];                 //  256 KB sin table
__device__ short  g_qb[(size_t)B_ * NH_  * S_ * HD_];    //  8.4 MB bf16 roped Q, scaled 0.125*log2e
__device__ short  g_kb[(size_t)B_ * NKV_ * S_ * HD_];    //  2.1 MB bf16 roped K [b][kvh][s][d]
// V^T in MFMA-A-frag blocked layout (ROUND-9 VERIFIED): [b][kvh][t=64][half=2][df=4][lane=64] x short4
// element (t,half,df,lane): V^T[d = df*16 + (lane&15)][kv = t*32 + half*16 + 4*(lane>>4) + i]
__device__ short  g_vts[(size_t)B_ * NKV_ * HD_ * S_];   //  2.1 MB
__device__ short  g_ao[(size_t)NTOK * NH_ * HD_];        //  8.4 MB bf16 attn out [tok][h*64+d]

static __device__ inline short f2bf(float f) {
  __hip_bfloat16 h = __float2bfloat16(f);     // RNE
  return *reinterpret_cast<short*>(&h);
}

// ---------------------------------------------------------------------------
// fp32 -> bf16 conversion of x and all weights (float4 in, short4 out),
// FUSED with the RoPE cos/sin table build (disjoint index range).
// ---------------------------------------------------------------------------
#define NX4   (NTOK * D_ / 4)                 // 1048576
#define NWQ4  (NH_ * HD_ * D_ / 4)            //  262144
#define NWK4  (NKV_ * HD_ * D_ / 4)           //   65536
#define NWV4  NWK4
#define NWO4  (D_ * NH_ * HD_ / 4)            //  262144
#define NCVT  (NX4 + NWQ4 + NWK4 + NWV4 + NWO4)
#define NRT   (S_ * 32)                       //   65536
#define NALL  (NCVT + NRT)

__global__ __launch_bounds__(256) void convert_all(const float* __restrict__ x,
                                                   const float* __restrict__ wq,
                                                   const float* __restrict__ wk,
                                                   const float* __restrict__ wv,
                                                   const float* __restrict__ wo) {
  int i = blockIdx.x * blockDim.x + threadIdx.x;
  if (i >= NALL) return;
  if (i >= NCVT) {
    // RoPE table entry: g_rc/g_rs[s*32 + d]
    const int j = i - NCVT;
    const int d = j & 31, s = j >> 5;
    const float inv = exp2f((float)d * (-13.287712379549449f / 32.0f));
    const float ang = (float)s * inv;
    float sn, cs;
    sincosf(ang, &sn, &cs);
    g_rc[j] = cs; g_rs[j] = sn;
    return;
  }
  const float* src; short* dst; int off;
  if (i < NX4)                          { src = x;  dst = g_xb;   off = i; }
  else if (i < NX4 + NWQ4)              { src = wq; dst = g_wqkv; off = i - NX4; }
  else if (i < NX4 + NWQ4 + NWK4)       { src = wk; dst = g_wqkv + (size_t)NWQ4 * 4;          off = i - NX4 - NWQ4; }
  else if (i < NX4 + NWQ4 + NWK4 + NWV4){ src = wv; dst = g_wqkv + (size_t)(NWQ4 + NWK4) * 4; off = i - NX4 - NWQ4 - NWK4; }
  else                                  { src = wo; dst = g_wob;  off = i - NX4 - NWQ4 - NWK4 - NWV4; }
  float4 v = ((const float4*)src)[off];
  short4 s;
  s.x = f2bf(v.x); s.y = f2bf(v.y); s.z = f2bf(v.z); s.w = f2bf(v.w);
  ((short4*)dst)[off] = s;
}

// ---------------------------------------------------------------------------
// GEMM1 + fused RoPE/scatter epilogue (ROUND-9 VERIFIED, unchanged).
//   nb 0..15  -> Q head nb   : rope, scale by 0.125*log2e, -> g_qb[b][h][s][d]
//   nb 16..19 -> K kvh nb-16 : rope,                        -> g_kb[b][kvh][s][d]
//   nb 20..23 -> V kvh nb-20 : blocked-transpose,           -> g_vts (A-frag layout)
// ---------------------------------------------------------------------------
__global__ __launch_bounds__(256) void gemm_qkv_rope() {
  const int w = threadIdx.x >> 6, lane = threadIdx.x & 63;
  const int m0 = blockIdx.x * 128 + w * 32;
  const int nb = blockIdx.y;
  const int n0 = nb * 64;
  const int lr = lane & 15, lk = (lane >> 4) * 8;

  f32x4 acc[2][4] = {};
  for (int k0 = 0; k0 < D_; k0 += 32) {
    short8 a0 = *(const short8*)(g_xb + (size_t)(m0 + lr) * D_ + k0 + lk);
    short8 a1 = *(const short8*)(g_xb + (size_t)(m0 + 16 + lr) * D_ + k0 + lk);
#pragma unroll
    for (int bj = 0; bj < 4; ++bj) {
      short8 bf = *(const short8*)(g_wqkv + (size_t)(n0 + bj * 16 + lr) * D_ + k0 + lk);
      acc[0][bj] = __builtin_amdgcn_mfma_f32_16x16x32_bf16(a0, bf, acc[0][bj], 0, 0, 0);
      acc[1][bj] = __builtin_amdgcn_mfma_f32_16x16x32_bf16(a1, bf, acc[1][bj], 0, 0, 0);
    }
  }
  const int rb = (lane >> 4) * 4;

  if (nb < 20) {
    const float sc = (nb < 16) ? 0.125f * LOG2E : 1.0f;
    short* const base = (nb < 16) ? g_qb : g_kb;
    const int hh = (nb < 16) ? nb : (nb - 16);
    const int nhh = (nb < 16) ? NH_ : NKV_;
#pragma unroll
    for (int af = 0; af < 2; ++af)
#pragma unroll
      for (int bj = 0; bj < 2; ++bj) {
        const int d0 = bj * 16 + lr;
#pragma unroll
        for (int r = 0; r < 4; ++r) {
          const int tok = m0 + af * 16 + rb + r;
          const int bI = tok >> 11, s = tok & (S_ - 1);
          const float c  = g_rc[s * 32 + d0];
          const float sn = g_rs[s * 32 + d0];
          const float lo = acc[af][bj][r], hi = acc[af][bj + 2][r];
          short* dp = base + (((size_t)(bI * nhh + hh)) * S_ + s) * HD_;
          dp[d0]      = f2bf((lo * c - hi * sn) * sc);
          dp[d0 + 32] = f2bf((hi * c + lo * sn) * sc);
        }
      }
  } else {
    // V: writer lane (g,l) holds exactly reader lane (g,l)'s A-frag quad.
    const int kvh = nb - 20;
#pragma unroll
    for (int af = 0; af < 2; ++af)
#pragma unroll
      for (int bj = 0; bj < 4; ++bj) {
        const int tok0 = m0 + af * 16 + rb;
        const int bI = tok0 >> 11, sl = tok0 & (S_ - 1);
        const int t = sl >> 5;
        const int half = (sl >> 4) & 1;
        short4 s4;
        s4.x = f2bf(acc[af][bj][0]); s4.y = f2bf(acc[af][bj][1]);
        s4.z = f2bf(acc[af][bj][2]); s4.w = f2bf(acc[af][bj][3]);
        *(short4*)(g_vts + ((((size_t)(bI * NKV_ + kvh) * 64 + t) * 2 + half) * 4 + bj) * 256
                         + lane * 4) = s4;
      }
  }
}

// ---------------------------------------------------------------------------
// MFMA flash attention, causal, GQA — SPLIT-KV over 4 waves per block
// (ROUND-9 VERIFIED, byte-identical). 16 q rows per block.
// Swapped QK^T (16x16x32): St[kv][q], lane (g,l) holds P[kv=mf*16+4g+r][q=l]
// == EXACTLY the B-frag of a K=16 MFMA. PV = 8x mfma_f32_16x16x16_bf16 with
// V^T A-frags from g_vts: ZERO cross-lane ops. P->bf16 via 4 v_cvt_pk.
// ---------------------------------------------------------------------------
__global__ __launch_bounds__(256) void attn_mfma() {
  const int bh  = blockIdx.x;                  // 0..31
  const int b   = bh >> 4, h = bh & 15;
  const int kvh = h >> 2;                      // REP = 4
  const int qw  = (int)(gridDim.y - 1 - blockIdx.y);   // heavy blocks dispatch first
  const int w   = threadIdx.x >> 6;            // wave 0..3
  const int lane = threadIdx.x & 63;
  const int g = lane >> 4, l = lane & 15;
  const int q0 = qw * 16;
  const int q_glob = q0 + l;

  const short* Qb  = g_qb + ((size_t)bh * S_ + q0) * HD_;
  const short* Kb  = g_kb + ((size_t)(b * NKV_ + kvh)) * S_ * HD_;
  const short* Vts = g_vts + (size_t)(b * NKV_ + kvh) * 64 * 2048 + lane * 4;

  short8 qf[2];
  qf[0] = *(const short8*)(Qb + l * HD_ + g * 8);
  qf[1] = *(const short8*)(Qb + l * HD_ + 32 + g * 8);

  f32x4 o[4] = {};                             // O^T acc: d = df*16 + g*4 + r, q = l
  float m_run = -1e30f, l_part = 0.0f;

  const int nt = (q0 >> 5) + 1;                // kv tiles of 32
  for (int t = w; t < nt; t += 4) {
    // ---- K frags (row-major, full-cacheline) + V A-frags (lane-major, coalesced)
    const short* Kt = Kb + (size_t)(t * 32) * HD_;
    short8 kf0 = *(const short8*)(Kt + l * HD_ + g * 8);
    short8 kf1 = *(const short8*)(Kt + (16 + l) * HD_ + g * 8);
    short8 kf2 = *(const short8*)(Kt + l * HD_ + 32 + g * 8);
    short8 kf3 = *(const short8*)(Kt + (16 + l) * HD_ + 32 + g * 8);
    const short* Vb = Vts + (size_t)t * 2048;
    short4v vfrag[2][4];
#pragma unroll
    for (int mf = 0; mf < 2; ++mf)
#pragma unroll
      for (int df = 0; df < 4; ++df)
        vfrag[mf][df] = *(const short4v*)(Vb + (mf * 4 + df) * 256);

    // ---- QK^T (swapped): St[kv][q]
    f32x4 st[2] = {};
    st[0] = __builtin_amdgcn_mfma_f32_16x16x32_bf16(kf0, qf[0], st[0], 0, 0, 0);
    st[1] = __builtin_amdgcn_mfma_f32_16x16x32_bf16(kf1, qf[0], st[1], 0, 0, 0);
    st[0] = __builtin_amdgcn_mfma_f32_16x16x32_bf16(kf2, qf[1], st[0], 0, 0, 0);
    st[1] = __builtin_amdgcn_mfma_f32_16x16x32_bf16(kf3, qf[1], st[1], 0, 0, 0);

    // ---- mask + per-lane max (8 scores of column q = l)
    float sv[2][4];
    float mt = -1e30f;
#pragma unroll
    for (int mf = 0; mf < 2; ++mf)
#pragma unroll
      for (int r = 0; r < 4; ++r) {
        const int kv = t * 32 + mf * 16 + g * 4 + r;
        float s = st[mf][r];
        s = (kv > q_glob) ? -1e30f : s;
        sv[mf][r] = s;
        mt = fmaxf(mt, s);
      }
    // ---- defer-max: rescale only when some column's max grew by > 8 (log2)
    if (__any(mt > m_run + 8.0f)) {
      float mr = mt;
      mr = fmaxf(mr, __shfl_xor(mr, 16, 64));
      mr = fmaxf(mr, __shfl_xor(mr, 32, 64));   // per-column max, uniform over g
      const float m_new = fmaxf(m_run, mr);
      const float alpha = exp2f(m_run - m_new);
      l_part *= alpha;
#pragma unroll
      for (int df = 0; df < 4; ++df)
#pragma unroll
        for (int r = 0; r < 4; ++r) o[df][r] *= alpha;
      m_run = m_new;
    }
    // ---- P = exp2(S - m); pack in-lane via v_cvt_pk; PV with K=16 MFMAs
#pragma unroll
    for (int mf = 0; mf < 2; ++mf) {
      float p0 = exp2f(sv[mf][0] - m_run);
      float p1 = exp2f(sv[mf][1] - m_run);
      float p2 = exp2f(sv[mf][2] - m_run);
      float p3 = exp2f(sv[mf][3] - m_run);
      l_part += (p0 + p1) + (p2 + p3);
      unsigned ulo, uhi;
      asm("v_cvt_pk_bf16_f32 %0, %1, %2" : "=v"(ulo) : "v"(p0), "v"(p1));
      asm("v_cvt_pk_bf16_f32 %0, %1, %2" : "=v"(uhi) : "v"(p2), "v"(p3));
      unsigned pw[2] = {ulo, uhi};
      short4v pf = *reinterpret_cast<const short4v*>(pw);
#pragma unroll
      for (int df = 0; df < 4; ++df)
        MFMA16(o[df], vfrag[mf][df], pf);
    }
  }

  // ---- per-wave l reduction over g-groups (uniform per column afterwards)
  float l1 = l_part + __shfl_xor(l_part, 16, 64);
  const float l_tot = l1 + __shfl_xor(l1, 32, 64);

  // ---- cross-wave merge via LDS
  __shared__ float lds_m[4][16];
  __shared__ float lds_l[4][16];
  __shared__ float lds_o[4][16][68];           // [wave][q][d], +4 pad vs 16-way conflict
  if (g == 0) { lds_m[w][l] = m_run; lds_l[w][l] = l_tot; }
#pragma unroll
  for (int df = 0; df < 4; ++df)
#pragma unroll
    for (int r = 0; r < 4; ++r)
      lds_o[w][l][df * 16 + g * 4 + r] = o[df][r];
  __syncthreads();

  // 256 threads: q = tid&15, d-group = tid>>4 (4 floats each)
  const int tid = threadIdx.x;
  const int q = tid & 15, dg = tid >> 4;
  float ms = lds_m[0][q];
#pragma unroll
  for (int w2 = 1; w2 < 4; ++w2) ms = fmaxf(ms, lds_m[w2][q]);
  float lsum = 0.0f;
  float od[4] = {0.0f, 0.0f, 0.0f, 0.0f};
#pragma unroll
  for (int w2 = 0; w2 < 4; ++w2) {
    const float sc = exp2f(lds_m[w2][q] - ms);   // 0 for empty waves
    lsum += lds_l[w2][q] * sc;
#pragma unroll
    for (int j = 0; j < 4; ++j) od[j] += sc * lds_o[w2][q][dg * 4 + j];
  }
  const float inv_l = 1.0f / lsum;
  short* optr = g_ao + ((size_t)(b * S_ + q0 + q)) * (NH_ * HD_) + h * HD_;
  short4 s4;
  s4.x = f2bf(od[0] * inv_l);
  s4.y = f2bf(od[1] * inv_l);
  s4.z = f2bf(od[2] * inv_l);
  s4.w = f2bf(od[3] * inv_l);
  *(short4*)(optr + dg * 4) = s4;
}

// ---------------------------------------------------------------------------
// GEMM2: out[4096][1024] = g_ao[4096][1024] @ wob[1024][1024]^T, fp32 out
// ---------------------------------------------------------------------------
__global__ __launch_bounds__(256) void gemm_out(float* __restrict__ out) {
  const int w = threadIdx.x >> 6, lane = threadIdx.x & 63;
  const int m0 = blockIdx.x * 128 + w * 32;
  const int n0 = blockIdx.y * 64;
  const int lr = lane & 15, lk = (lane >> 4) * 8;
  const int K = NH_ * HD_;               // 1024

  f32x4 acc[2][4] = {};
  for (int k0 = 0; k0 < K; k0 += 32) {
    short8 a0 = *(const short8*)(g_ao + (size_t)(m0 + lr) * K + k0 + lk);
    short8 a1 = *(const short8*)(g_ao + (size_t)(m0 + 16 + lr) * K + k0 + lk);
#pragma unroll
    for (int bj = 0; bj < 4; ++bj) {
      short8 bf = *(const short8*)(g_wob + (size_t)(n0 + bj * 16 + lr) * K + k0 + lk);
      acc[0][bj] = __builtin_amdgcn_mfma_f32_16x16x32_bf16(a0, bf, acc[0][bj], 0, 0, 0);
      acc[1][bj] = __builtin_amdgcn_mfma_f32_16x16x32_bf16(a1, bf, acc[1][bj], 0, 0, 0);
    }
  }
  const int rb = (lane >> 4) * 4;
#pragma unroll
  for (int af = 0; af < 2; ++af)
#pragma unroll
    for (int bj = 0; bj < 4; ++bj)
#pragma unroll
      for (int r = 0; r < 4; ++r)
        out[(size_t)(m0 + af * 16 + rb + r) * D_ + n0 + bj * 16 + lr] =
            acc[af][bj][r];
}

// ---------------------------------------------------------------------------
extern "C" void kernel_launch(void* const* d_in, const int* in_sizes, int n_in,
                              void* d_out, int out_size, void* d_ws, size_t ws_size,
                              hipStream_t stream) {
  const float* x  = (const float*)d_in[0];   // float32 per reference
  const float* Wq = (const float*)d_in[1];
  const float* Wk = (const float*)d_in[2];
  const float* Wv = (const float*)d_in[3];
  const float* Wo = (const float*)d_in[4];
  float* out = (float*)d_out;

  convert_all<<<(NALL + 255) / 256, 256, 0, stream>>>(x, Wq, Wk, Wv, Wo);
  {
    dim3 g(NTOK / 128, QKVN / 64);            // 32 x 24
    gemm_qkv_rope<<<g, 256, 0, stream>>>();
  }
  {
    dim3 g(B_ * NH_, S_ / 16);                // 32 bh x 128 q-blocks, 4 waves each
    attn_mfma<<<g, 256, 0, stream>>>();
  }
  {
    dim3 g(NTOK / 128, D_ / 64);              // 32 x 16
    gemm_out<<<g, 256, 0, stream>>>(out);
  }
}